// Round 4
// baseline (302.732 us; speedup 1.0000x reference)
//
#include <hip/hip_runtime.h>
#include <hip/hip_bf16.h>
#include <stdint.h>

typedef unsigned short u16;
using bf16x8 = __attribute__((ext_vector_type(8))) __bf16;
using f32x4  = __attribute__((ext_vector_type(4))) float;

// fp32 -> bf16 (round-to-nearest-even), as raw bits
__device__ __forceinline__ u16 f2bf(float f) {
    union { float f; unsigned u; } a; a.f = f;
    unsigned u = a.u;
    u += 0x7fffu + ((u >> 16) & 1u);
    return (u16)(u >> 16);
}
__device__ __forceinline__ float bf2f(unsigned bits_hi16) {
    union { unsigned u; float f; } a; a.u = bits_hi16; return a.f;
}

// async global->LDS, 16 bytes per lane (global_load_lds_dwordx4)
__device__ __forceinline__ void gload_lds16(const void* g, void* l) {
    __builtin_amdgcn_global_load_lds(
        (const __attribute__((address_space(1))) void*)g,
        (__attribute__((address_space(3))) void*)l, 16, 0, 0);
}

// Bijective XCD-aware swizzle (T1); requires nwg % 8 == 0.
__device__ __forceinline__ void xcd_swz(int nx, int ny, int& x, int& y, int& z) {
    const int flat = (int)blockIdx.x + nx * ((int)blockIdx.y + ny * (int)blockIdx.z);
    const int cpx = (nx * ny * (int)gridDim.z) >> 3;  // chunk per XCD
    const int s = (flat & 7) * cpx + (flat >> 3);
    x = s % nx;
    const int t = s / nx;
    y = t % ny;
    z = t / ny;
}

// ---------------------------------------------------------------------------
// Legacy 128x128-tile bf16 GEMM core (m97 structure), C = A @ B^T.
// Still used by proj/vproj.
// ---------------------------------------------------------------------------
__device__ __forceinline__ void gemm_core(const u16* __restrict__ A,
                                          const u16* __restrict__ B,
                                          int lda, int ldb, int kLen,
                                          int bm, int bn,
                                          u16* sA, u16* sB,
                                          f32x4 acc[4][4])
{
    const int tid  = threadIdx.x;
    const int lane = tid & 63;
    const int wm   = (tid >> 7) & 1;
    const int wn   = (tid >> 6) & 1;

    const u16* Ag0 = A + (long)(bm * 128 + (tid >> 2)) * lda + (tid & 3) * 8;
    const u16* Ag1 = Ag0 + (long)64 * lda;
    const u16* Bg0 = B + (long)(bn * 128 + (tid >> 2)) * ldb + (tid & 3) * 8;
    const u16* Bg1 = Bg0 + (long)64 * ldb;
    u16* la = sA + tid * 8;
    u16* lb = sB + tid * 8;

    const int rfo  = (wm * 64 + (lane & 15)) * 32 + (lane >> 4) * 8;
    const int rfoB = (wn * 64 + (lane & 15)) * 32 + (lane >> 4) * 8;

    for (int k0 = 0; k0 < kLen; k0 += 64) {
        gload_lds16(Ag0 + k0, la);
        gload_lds16(Ag1 + k0, la + 2048);
        gload_lds16(Bg0 + k0, lb);
        gload_lds16(Bg1 + k0, lb + 2048);
        gload_lds16(Ag0 + k0 + 32, la + 4096);
        gload_lds16(Ag1 + k0 + 32, la + 6144);
        gload_lds16(Bg0 + k0 + 32, lb + 4096);
        gload_lds16(Bg1 + k0 + 32, lb + 6144);
        __syncthreads();
#pragma unroll
        for (int h = 0; h < 2; h++) {
            const u16* ra = sA + h * 4096 + rfo;
            const u16* rb = sB + h * 4096 + rfoB;
            bf16x8 af[4], bfr[4];
#pragma unroll
            for (int i = 0; i < 4; i++) af[i]  = *(const bf16x8*)(ra + i * 512);
#pragma unroll
            for (int i = 0; i < 4; i++) bfr[i] = *(const bf16x8*)(rb + i * 512);
#pragma unroll
            for (int mi = 0; mi < 4; mi++)
#pragma unroll
                for (int ni = 0; ni < 4; ni++)
                    acc[mi][ni] = __builtin_amdgcn_mfma_f32_16x16x32_bf16(
                        af[mi], bfr[ni], acc[mi][ni], 0, 0, 0);
        }
        __syncthreads();
    }
}

// ---------------------------------------------------------------------------
// 256x256-tile, 8-wave fine-grained pipelined GEMM core (m201-style).
// C = A @ B^T over K = T*64.
//
// LDS 128 KB: 2 tile-buffers x { A:[2 kh][256 r][32 c] u16 @0/8192,
//                                B: same @16384/24576 }.
// Bank swizzle: LDS[r][slot16] = G[r][slot16 ^ ((r>>1)&3)] via pre-swizzled
// global source (gload_lds dest linear); read-side XOR is a per-lane const.
//
// 4 phases per K-tile t, each phase:
//   { ds_read frags (4 or 8) ; stage one 2-load unit of tile t+1 -> buf^1 ;
//     [vmcnt(4) at ph2/ph4] ; barrier ; lgkm(0)+sched_barrier ; 16 MFMA ;
//     barrier }
// Stage units: ph1=A_kh0, ph2=B_kh0, ph3=A_kh1, ph4=B_kh1 (of tile t+1).
// vmcnt(4) BEFORE the barrier: per-wave counts compose block-wide, so
//   ph1(t) frags (kh0 of t) are resident via vmcnt(4)@ph4(t-1), and
//   ph3(t) frags (kh1 of t) via vmcnt(4)@ph2(t).
// Region overwrite safety: buf^1's last reads were lgkm(0)-drained >=1
// phase-pair before any stage into it (barrier-ordered, all waves).
// Tail: stage clamps to T-1 (rewrites same bytes into the dead buffer) so
// vmcnt arithmetic is uniform for every t.
// ---------------------------------------------------------------------------
__device__ __forceinline__ void gemm256_core(const u16* __restrict__ A,
                                             const u16* __restrict__ B,
                                             int lda, int ldb, int T,
                                             int rowA0, int rowB0,
                                             u16* lds,
                                             f32x4 acc[8][4],
                                             int wm, int wn)
{
    const int l = (int)threadIdx.x & 63;
    const int w = (int)threadIdx.x >> 6;

    // staging: wave w rows [w*32, w*32+32): lane -> row w*32+(l>>2), slot l&3
    const int srcswz = 8 * ((l & 3) ^ ((l >> 3) & 3));
    const u16* pA = A + (long)(rowA0 + w * 32 + (l >> 2)) * lda + srcswz;
    const u16* pB = B + (long)(rowB0 + w * 32 + (l >> 2)) * ldb + srcswz;
    const int dstb = w * 1024 + l * 8;

    // fragment read bases (swizzle constant per lane)
    const int fsw = 8 * ((l >> 4) ^ ((l >> 1) & 3));
    const int fA = (wm * 128 + (l & 15)) * 32 + fsw;
    const int fB = (wn * 64  + (l & 15)) * 32 + fsw;

    bf16x8 alo[4], ahi[4], bk0[4], bk1[4];

#define STG_A(tile, kh)                                                        \
    {                                                                          \
        const u16* s = pA + (long)(tile) * 64 + (kh) * 32;                     \
        u16* d = lds + (((tile) & 1) << 15) + ((kh) << 13) + dstb;             \
        gload_lds16(s, d);                                                     \
        gload_lds16(s + 16 * (long)lda, d + 512);                              \
    }
#define STG_B(tile, kh)                                                        \
    {                                                                          \
        const u16* s = pB + (long)(tile) * 64 + (kh) * 32;                     \
        u16* d = lds + (((tile) & 1) << 15) + ((kh) << 13) + 16384 + dstb;     \
        gload_lds16(s, d);                                                     \
        gload_lds16(s + 16 * (long)ldb, d + 512);                              \
    }
#define RD_A(dst, tile, ks, mih)                                               \
    {                                                                          \
        const u16* Ar = lds + (((tile) & 1) << 15) + ((ks) << 13) + fA +       \
                        (mih) * 2048;                                          \
        _Pragma("unroll")                                                      \
        for (int i = 0; i < 4; i++) dst[i] = *(const bf16x8*)(Ar + i * 512);   \
    }
#define RD_B(dst, tile, ks)                                                    \
    {                                                                          \
        const u16* Br = lds + (((tile) & 1) << 15) + ((ks) << 13) + 16384 + fB;\
        _Pragma("unroll")                                                      \
        for (int i = 0; i < 4; i++) dst[i] = *(const bf16x8*)(Br + i * 512);   \
    }
#define MF16(a_, b_, lo)                                                       \
    {                                                                          \
        __builtin_amdgcn_s_setprio(1);                                         \
        _Pragma("unroll")                                                      \
        for (int mi = 0; mi < 4; mi++)                                         \
            _Pragma("unroll")                                                  \
            for (int ni = 0; ni < 4; ni++)                                     \
                acc[(lo) + mi][ni] = __builtin_amdgcn_mfma_f32_16x16x32_bf16(  \
                    a_[mi], b_[ni], acc[(lo) + mi][ni], 0, 0, 0);              \
        __builtin_amdgcn_s_setprio(0);                                         \
    }
#define BAR()  __builtin_amdgcn_s_barrier()
#define LGKM0()                                                                \
    {                                                                          \
        asm volatile("s_waitcnt lgkmcnt(0)" ::: "memory");                     \
        __builtin_amdgcn_sched_barrier(0);                                     \
    }
#define VM4() asm volatile("s_waitcnt vmcnt(4)" ::: "memory")

    // ---- prologue: stage tile0 (kh0 then kh1); kh0 resident, kh1 in flight
    STG_A(0, 0); STG_B(0, 0);
    STG_A(0, 1); STG_B(0, 1);
    VM4();
    BAR();

    for (int t = 0; t < T; ++t) {
        const int ts = (t + 1 < T) ? t + 1 : T - 1;  // clamp: dead-buffer rewrite

        // ---- ph1: frags (t, ks0, mi0-3 + B) ; stage A_kh0(t+1)
        RD_A(alo, t, 0, 0); RD_B(bk0, t, 0);
        STG_A(ts, 0);
        BAR(); LGKM0();
        MF16(alo, bk0, 0);
        BAR();

        // ---- ph2: frags (t, ks0, mi4-7) ; stage B_kh0(t+1)
        RD_A(ahi, t, 0, 1);
        STG_B(ts, 0);
        VM4();               // retires A_kh1(t), B_kh1(t) -> ph3 safe
        BAR(); LGKM0();
        MF16(ahi, bk0, 4);
        BAR();

        // ---- ph3: frags (t, ks1, mi0-3 + B) ; stage A_kh1(t+1)
        RD_A(alo, t, 1, 0); RD_B(bk1, t, 1);
        STG_A(ts, 1);
        BAR(); LGKM0();
        MF16(alo, bk1, 0);
        BAR();

        // ---- ph4: frags (t, ks1, mi4-7) ; stage B_kh1(t+1)
        RD_A(ahi, t, 1, 1);
        STG_B(ts, 1);
        VM4();               // retires A_kh0(t+1), B_kh0(t+1) -> next ph1 safe
        BAR(); LGKM0();
        MF16(ahi, bk1, 4);
        BAR();
    }
    asm volatile("s_waitcnt vmcnt(0)" ::: "memory");  // drain tail stages

#undef STG_A
#undef STG_B
#undef RD_A
#undef RD_B
#undef MF16
#undef BAR
#undef LGKM0
#undef VM4
}

// ---------------------------------------------------------------------------
// Kernel 1: fp32 -> bf16 casts
// ---------------------------------------------------------------------------
__global__ __launch_bounds__(256)
void cast6(const float* __restrict__ q, const float* __restrict__ k,
           const float* __restrict__ v, const float* __restrict__ wq,
           const float* __restrict__ wk, const float* __restrict__ wv,
           u16* __restrict__ qb, u16* __restrict__ kb, u16* __restrict__ vb,
           u16* __restrict__ wqb, u16* __restrict__ wkb, u16* __restrict__ wvb,
           int nqkv, int nw)
{
    const int z = blockIdx.y;
    const float* s; u16* d; int n;
    switch (z) {
        case 0:  s = q;  d = qb;  n = nqkv; break;
        case 1:  s = k;  d = kb;  n = nqkv; break;
        case 2:  s = v;  d = vb;  n = nqkv; break;
        case 3:  s = wq; d = wqb; n = nw;   break;
        case 4:  s = wk; d = wkb; n = nw;   break;
        default: s = wv; d = wvb; n = nw;   break;
    }
    long i = ((long)blockIdx.x * 256 + threadIdx.x) * 8;
    if (i >= n) return;
    float4 a = *(const float4*)(s + i);
    float4 b = *(const float4*)(s + i + 4);
    ushort4 o0, o1;
    o0.x = f2bf(a.x); o0.y = f2bf(a.y); o0.z = f2bf(a.z); o0.w = f2bf(a.w);
    o1.x = f2bf(b.x); o1.y = f2bf(b.y); o1.z = f2bf(b.z); o1.w = f2bf(b.w);
    *(ushort4*)(d + i)     = o0;
    *(ushort4*)(d + i + 4) = o1;
}

// ---------------------------------------------------------------------------
// Kernel 2: QK projections (z=0: qp, z=1: kp)
// ---------------------------------------------------------------------------
__global__ __launch_bounds__(256, 2)
void proj_gemm(const u16* __restrict__ qb, const u16* __restrict__ kb,
               const u16* __restrict__ vb, const u16* __restrict__ wqb,
               const u16* __restrict__ wkb, const u16* __restrict__ wvb,
               const float* __restrict__ bq, const float* __restrict__ bk,
               const float* __restrict__ bv,
               u16* __restrict__ qp, u16* __restrict__ kp, u16* __restrict__ vpT)
{
    __shared__ __align__(16) u16 sA[8192];
    __shared__ __align__(16) u16 sB[8192];
    int bx, by, bz;
    xcd_swz(8, 32, bx, by, bz);
    const int z = bz;
    const u16* A = (z == 0) ? qb : (z == 1) ? kb : vb;
    const u16* B = (z == 0) ? wqb : (z == 1) ? wkb : wvb;
    const float* bias = (z == 0) ? bq : (z == 1) ? bk : bv;
    u16* OUT = (z == 0) ? qp : (z == 1) ? kp : vpT;
    const float scale = (z == 0) ? 0.03125f : 1.0f;  // 1024^-0.5

    f32x4 acc[4][4] = {};
    gemm_core(A, B, 1024, 1024, 1024, by, bx, sA, sB, acc);

    const int lane = threadIdx.x & 63;
    const int wm   = (threadIdx.x >> 7) & 1;
    const int wn   = (threadIdx.x >> 6) & 1;
    const int m0 = by * 128 + wm * 64 + ((lane >> 4) << 2);
    const int n0 = bx * 128 + wn * 64 + (lane & 15);
#pragma unroll
    for (int mi = 0; mi < 4; mi++)
#pragma unroll
        for (int ni = 0; ni < 4; ni++) {
            const int gm = m0 + mi * 16;
            const int gn = n0 + ni * 16;
            const float bb = bias[gn];
#pragma unroll
            for (int r = 0; r < 4; r++) {
                float val = (acc[mi][ni][r] + bb) * scale;
                if (z < 2) OUT[(long)(gm + r) * 1024 + gn] = f2bf(val);
                else       OUT[(long)gn * 4096 + gm + r]   = f2bf(val);
            }
        }
}

// ---------------------------------------------------------------------------
// Kernel 2b: vpT = Wv @ v^T + bv (per-row)  [1024 x 4096]
// ---------------------------------------------------------------------------
__global__ __launch_bounds__(256, 2)
void vproj_gemm(const u16* __restrict__ wvb, const u16* __restrict__ vb,
                const float* __restrict__ bv, u16* __restrict__ vpT)
{
    __shared__ __align__(16) u16 sA[8192];
    __shared__ __align__(16) u16 sB[8192];
    f32x4 acc[4][4] = {};
    gemm_core(wvb, vb, 1024, 1024, 1024, blockIdx.y, blockIdx.x, sA, sB, acc);

    const int lane = threadIdx.x & 63;
    const int wm   = (threadIdx.x >> 7) & 1;
    const int wn   = (threadIdx.x >> 6) & 1;
    const int m0 = blockIdx.y * 128 + wm * 64 + ((lane >> 4) << 2);
    const int n0 = blockIdx.x * 128 + wn * 64 + (lane & 15);
#pragma unroll
    for (int mi = 0; mi < 4; mi++)
#pragma unroll
        for (int ni = 0; ni < 4; ni++) {
            const int gm = m0 + mi * 16;
            const int gn = n0 + ni * 16;
#pragma unroll
            for (int r = 0; r < 4; r++)
                vpT[(long)(gm + r) * 4096 + gn] = f2bf(acc[mi][ni][r] + bv[gm + r]);
        }
}

// ---------------------------------------------------------------------------
// Kernel 3: scores = qp @ kp^T -> bf16 S. 256x256 fine-grained core.
// ---------------------------------------------------------------------------
__global__ __launch_bounds__(512, 2)
void score_gemm256(const u16* __restrict__ qp, const u16* __restrict__ kp,
                   u16* __restrict__ S)
{
    __shared__ __align__(16) u16 lds[65536];  // 128 KB

    const int flat = (int)blockIdx.x + ((int)blockIdx.y << 4);
    const int sfl = (flat & 7) * 32 + (flat >> 3);
    const int bx = sfl & 15;   // N tile
    const int by = sfl >> 4;   // M tile

    const int l  = (int)threadIdx.x & 63;
    const int w  = (int)threadIdx.x >> 6;
    const int wm = w >> 2;
    const int wn = w & 3;

    f32x4 acc[8][4] = {};
    gemm256_core(qp, kp, 1024, 1024, 16, by * 256, bx * 256, lds, acc, wm, wn);

    const int gm0 = by * 256 + wm * 128 + ((l >> 4) << 2);
    const int gn0 = bx * 256 + wn * 64 + (l & 15);
#pragma unroll
    for (int mi = 0; mi < 8; mi++)
#pragma unroll
        for (int ni = 0; ni < 4; ni++) {
            const int gm = gm0 + mi * 16;
            const int gn = gn0 + ni * 16;
#pragma unroll
            for (int r = 0; r < 4; r++)
                S[(long)(gm + r) * 4096 + gn] = f2bf(acc[mi][ni][r]);
        }
}

// ---------------------------------------------------------------------------
// Kernel 4: att = softmax(S_bf16, axis=-1) + bias, cast to bf16. Block per row.
// ---------------------------------------------------------------------------
__global__ __launch_bounds__(256)
void softmax_bias(const u16* __restrict__ S, const float* __restrict__ bias,
                  u16* __restrict__ att)
{
    const long row = blockIdx.x;
    const int tid = threadIdx.x;
    const u16* srow = S + row * 4096 + tid * 16;

    float v[16];
    {
        uint4 a = *(const uint4*)(srow);
        uint4 b = *(const uint4*)(srow + 8);
        unsigned w[8] = {a.x, a.y, a.z, a.w, b.x, b.y, b.z, b.w};
#pragma unroll
        for (int i = 0; i < 8; i++) {
            v[2 * i]     = bf2f(w[i] << 16);
            v[2 * i + 1] = bf2f(w[i] & 0xffff0000u);
        }
    }
    float mx = v[0];
#pragma unroll
    for (int i = 1; i < 16; i++) mx = fmaxf(mx, v[i]);
#pragma unroll
    for (int o = 32; o >= 1; o >>= 1) mx = fmaxf(mx, __shfl_xor(mx, o, 64));
    __shared__ float red[8];
    if ((tid & 63) == 0) red[tid >> 6] = mx;
    __syncthreads();
    mx = fmaxf(fmaxf(red[0], red[1]), fmaxf(red[2], red[3]));
    float sum = 0.f;
#pragma unroll
    for (int i = 0; i < 16; i++) { v[i] = __expf(v[i] - mx); sum += v[i]; }
#pragma unroll
    for (int o = 32; o >= 1; o >>= 1) sum += __shfl_xor(sum, o, 64);
    if ((tid & 63) == 0) red[4 + (tid >> 6)] = sum;
    __syncthreads();
    const float inv = 1.0f / (red[4] + red[5] + red[6] + red[7]);

    const float4* brow = (const float4*)(bias + row * 4096 + tid * 16);
    unsigned o[8];
#pragma unroll
    for (int i = 0; i < 4; i++) {
        float4 b = brow[i];
        unsigned lo = f2bf(v[4 * i + 0] * inv + b.x);
        unsigned hi = f2bf(v[4 * i + 1] * inv + b.y);
        o[2 * i] = lo | (hi << 16);
        lo = f2bf(v[4 * i + 2] * inv + b.z);
        hi = f2bf(v[4 * i + 3] * inv + b.w);
        o[2 * i + 1] = lo | (hi << 16);
    }
    u16* arow = att + row * 4096 + tid * 16;
    *(uint4*)(arow)     = make_uint4(o[0], o[1], o[2], o[3]);
    *(uint4*)(arow + 8) = make_uint4(o[4], o[5], o[6], o[7]);
}

// ---------------------------------------------------------------------------
// Kernel 5: split-K=4: P[z] = att[:, z*1024..] @ vpT[:, z*1024..]^T, fp32.
// 256x256 fine-grained core. Grid (4, 16, 4) = 256 blocks, 1/CU.
// ---------------------------------------------------------------------------
__global__ __launch_bounds__(512, 2)
void out_gemm256(const u16* __restrict__ att, const u16* __restrict__ vpT,
                 float* __restrict__ P)
{
    __shared__ __align__(16) u16 lds[65536];  // 128 KB

    int bx, by, bz;
    xcd_swz(4, 16, bx, by, bz);
    const u16* A = att + bz * 1024;
    const u16* B = vpT + bz * 1024;
    float* O = P + (long)bz * 4096 * 1024;

    const int l  = (int)threadIdx.x & 63;
    const int w  = (int)threadIdx.x >> 6;
    const int wm = w >> 2;
    const int wn = w & 3;

    f32x4 acc[8][4] = {};
    gemm256_core(A, B, 4096, 4096, 16, by * 256, bx * 256, lds, acc, wm, wn);

    const int gm0 = by * 256 + wm * 128 + ((l >> 4) << 2);
    const int gn0 = bx * 256 + wn * 64 + (l & 15);
#pragma unroll
    for (int mi = 0; mi < 8; mi++)
#pragma unroll
        for (int ni = 0; ni < 4; ni++) {
            const int gm = gm0 + mi * 16;
            const int gn = gn0 + ni * 16;
#pragma unroll
            for (int r = 0; r < 4; r++)
                O[(long)(gm + r) * 1024 + gn] = acc[mi][ni][r];
        }
}

// ---------------------------------------------------------------------------
// Kernel 6: out = P0 + P1 + P2 + P3  (fp32), 4096x1024
// ---------------------------------------------------------------------------
__global__ __launch_bounds__(256)
void addp4(const float* __restrict__ P, float* __restrict__ O)
{
    long i = ((long)blockIdx.x * 256 + threadIdx.x) * 4;
    const long st = 4194304;
    float4 a = *(const float4*)(P + i);
    float4 b = *(const float4*)(P + st + i);
    float4 c = *(const float4*)(P + 2 * st + i);
    float4 d = *(const float4*)(P + 3 * st + i);
    float4 r;
    r.x = (a.x + b.x) + (c.x + d.x);
    r.y = (a.y + b.y) + (c.y + d.y);
    r.z = (a.z + b.z) + (c.z + d.z);
    r.w = (a.w + b.w) + (c.w + d.w);
    *(float4*)(O + i) = r;
}

// ---------------------------------------------------------------------------
extern "C" void kernel_launch(void* const* d_in, const int* in_sizes, int n_in,
                              void* d_out, int out_size, void* d_ws, size_t ws_size,
                              hipStream_t stream)
{
    const float* q    = (const float*)d_in[0];
    const float* k    = (const float*)d_in[1];
    const float* v    = (const float*)d_in[2];
    const float* bias = (const float*)d_in[3];
    const float* Wq   = (const float*)d_in[4];
    const float* bq   = (const float*)d_in[5];
    const float* Wk   = (const float*)d_in[6];
    const float* bk   = (const float*)d_in[7];
    const float* Wv   = (const float*)d_in[8];
    const float* bv   = (const float*)d_in[9];
    float* out = (float*)d_out;

    uint8_t* ws = (uint8_t*)d_ws;
    const size_t MB = 1u << 20;
    // layout (118 MB):
    //   [0,8)    qb   [8,16) kb   [16,24) vb        (dead after proj/vproj)
    //   [24,26)  wqb  [26,28) wkb [28,30) wvb       (dead after proj/vproj)
    //   [30,38)  qp   [38,46) kp                    (dead after score)
    //   [46,54)  vpT
    //   [54,86)  S (bf16 scores, 32MB)              (dead after softmax)
    //   [0,32)   att (bf16, 32MB) -- aliases dead qb/kb/vb region
    //   [54,118) P (4x fp32 partials, 16MB each) -- aliases dead S
    u16* qb  = (u16*)(ws);
    u16* kb  = (u16*)(ws + 8 * MB);
    u16* vb  = (u16*)(ws + 16 * MB);
    u16* wqb = (u16*)(ws + 24 * MB);
    u16* wkb = (u16*)(ws + 26 * MB);
    u16* wvb = (u16*)(ws + 28 * MB);
    u16* qp  = (u16*)(ws + 30 * MB);
    u16* kp  = (u16*)(ws + 38 * MB);
    u16* vpT = (u16*)(ws + 46 * MB);
    u16* S   = (u16*)(ws + 54 * MB);
    u16* att = (u16*)(ws);
    float* P = (float*)(ws + 54 * MB);

    cast6<<<dim3(2048, 6), 256, 0, stream>>>(q, k, v, Wq, Wk, Wv,
                                             qb, kb, vb, wqb, wkb, wvb,
                                             4096 * 1024, 1024 * 1024);
    proj_gemm<<<dim3(8, 32, 2), 256, 0, stream>>>(qb, kb, vb, wqb, wkb, wvb,
                                                  bq, bk, bv, qp, kp, vpT);
    vproj_gemm<<<dim3(32, 8), 256, 0, stream>>>(wvb, vb, bv, vpT);
    score_gemm256<<<dim3(16, 16), 512, 0, stream>>>(qp, kp, S);
    softmax_bias<<<dim3(4096), 256, 0, stream>>>(S, bias, att);
    out_gemm256<<<dim3(4, 16, 4), 512, 0, stream>>>(att, vpT, P);
    addp4<<<dim3(4096), 256, 0, stream>>>(P, out);
}

// Round 6
// 296.356 us; speedup vs baseline: 1.0215x; 1.0215x over previous
//
#include <hip/hip_runtime.h>
#include <hip/hip_bf16.h>
#include <stdint.h>

typedef unsigned short u16;
using bf16x8 = __attribute__((ext_vector_type(8))) __bf16;
using f32x4  = __attribute__((ext_vector_type(4))) float;
using f32x16 = __attribute__((ext_vector_type(16))) float;

// fp32 -> bf16 (round-to-nearest-even), as raw bits
__device__ __forceinline__ u16 f2bf(float f) {
    union { float f; unsigned u; } a; a.f = f;
    unsigned u = a.u;
    u += 0x7fffu + ((u >> 16) & 1u);
    return (u16)(u >> 16);
}
__device__ __forceinline__ float bf2f(unsigned bits_hi16) {
    union { unsigned u; float f; } a; a.u = bits_hi16; return a.f;
}

// async global->LDS, 16 bytes per lane (global_load_lds_dwordx4)
__device__ __forceinline__ void gload_lds16(const void* g, void* l) {
    __builtin_amdgcn_global_load_lds(
        (const __attribute__((address_space(1))) void*)g,
        (__attribute__((address_space(3))) void*)l, 16, 0, 0);
}

// Bijective XCD-aware swizzle (T1); requires nwg % 8 == 0.
__device__ __forceinline__ void xcd_swz(int nx, int ny, int& x, int& y, int& z) {
    const int flat = (int)blockIdx.x + nx * ((int)blockIdx.y + ny * (int)blockIdx.z);
    const int cpx = (nx * ny * (int)gridDim.z) >> 3;  // chunk per XCD
    const int s = (flat & 7) * cpx + (flat >> 3);
    x = s % nx;
    const int t = s / nx;
    y = t % ny;
    z = t / ny;
}

// ---------------------------------------------------------------------------
// Legacy 128x128-tile bf16 GEMM core (m97 structure), C = A @ B^T.
// Used by proj (QKV projections).
// ---------------------------------------------------------------------------
__device__ __forceinline__ void gemm_core(const u16* __restrict__ A,
                                          const u16* __restrict__ B,
                                          int lda, int ldb, int kLen,
                                          int bm, int bn,
                                          u16* sA, u16* sB,
                                          f32x4 acc[4][4])
{
    const int tid  = threadIdx.x;
    const int lane = tid & 63;
    const int wm   = (tid >> 7) & 1;
    const int wn   = (tid >> 6) & 1;

    const u16* Ag0 = A + (long)(bm * 128 + (tid >> 2)) * lda + (tid & 3) * 8;
    const u16* Ag1 = Ag0 + (long)64 * lda;
    const u16* Bg0 = B + (long)(bn * 128 + (tid >> 2)) * ldb + (tid & 3) * 8;
    const u16* Bg1 = Bg0 + (long)64 * ldb;
    u16* la = sA + tid * 8;
    u16* lb = sB + tid * 8;

    const int rfo  = (wm * 64 + (lane & 15)) * 32 + (lane >> 4) * 8;
    const int rfoB = (wn * 64 + (lane & 15)) * 32 + (lane >> 4) * 8;

    for (int k0 = 0; k0 < kLen; k0 += 64) {
        gload_lds16(Ag0 + k0, la);
        gload_lds16(Ag1 + k0, la + 2048);
        gload_lds16(Bg0 + k0, lb);
        gload_lds16(Bg1 + k0, lb + 2048);
        gload_lds16(Ag0 + k0 + 32, la + 4096);
        gload_lds16(Ag1 + k0 + 32, la + 6144);
        gload_lds16(Bg0 + k0 + 32, lb + 4096);
        gload_lds16(Bg1 + k0 + 32, lb + 6144);
        __syncthreads();
#pragma unroll
        for (int h = 0; h < 2; h++) {
            const u16* ra = sA + h * 4096 + rfo;
            const u16* rb = sB + h * 4096 + rfoB;
            bf16x8 af[4], bfr[4];
#pragma unroll
            for (int i = 0; i < 4; i++) af[i]  = *(const bf16x8*)(ra + i * 512);
#pragma unroll
            for (int i = 0; i < 4; i++) bfr[i] = *(const bf16x8*)(rb + i * 512);
#pragma unroll
            for (int mi = 0; mi < 4; mi++)
#pragma unroll
                for (int ni = 0; ni < 4; ni++)
                    acc[mi][ni] = __builtin_amdgcn_mfma_f32_16x16x32_bf16(
                        af[mi], bfr[ni], acc[mi][ni], 0, 0, 0);
        }
        __syncthreads();
    }
}

// ---------------------------------------------------------------------------
// 256x256-tile, 8-wave, register-double-buffered GEMM core, 32x32x16 MFMA.
// C = A @ B^T over K = T*64. Per-wave output 128x64 = 4x2 frags of 32x32.
//
// LDS 128 KB: 2 tile-buffers x { A:[2 kh][256 r][32 c] u16 @0/8192,
//                                B: same @16384/24576 } (u16 offsets).
// Bank swizzle: LDS[r][slot16] = G[r][slot16 ^ ((r>>1)&3)] via pre-swizzled
// global source (gload_lds dest stays linear); read-side XOR folds into
// per-lane constants s0/s1. Verified conflict-free for the 32x32 frag reads.
//
// Frag layouts (guide-verified):
//   A/B in: lane l -> row l&31, k = (l>>5)*8 + j   (8 bf16 = 1 ds_read_b128)
//   C/D:    col = l&31, row = (r&3) + 8*(r>>2) + 4*(l>>5),  r in [0,16)
//
// Pipeline per K-tile t (buf b=t&1; frag set0 = K-half0, set1 = K-half1):
//  ph1: ds_read set1 <- (t,ksh1)  ; MFMA mi0-1 set0
//  ph2: stage kh0(t+2)->buf b     ; MFMA mi2-3 set0 ; lgkm(0); vmcnt(4); BAR
//  ph3: ds_read set0 <- (t+1,ksh0); MFMA mi0-1 set1
//  ph4: stage kh1(t+2)->buf b     ; MFMA mi2-3 set1 ; lgkm(0); BAR
// vmcnt(4) PRE-barrier => residency composes block-wide (fixes R3's race):
// it retires (t+1,kh0)+(t+1,kh1), guarding ph3(t) and ph1(t+1) reads.
// lgkm(0)+BAR at ph2/ph4 = exact cross-wave guard before region overwrite.
// Tail: stage clamps to T-1 (rewrites same bytes) so counts stay uniform.
// ---------------------------------------------------------------------------
__device__ __forceinline__ void gemm256_core(const u16* __restrict__ A,
                                             const u16* __restrict__ B,
                                             int lda, int ldb, int T,
                                             int rowA0, int rowB0,
                                             u16* lds,
                                             f32x16 acc[4][2],
                                             int wm, int wn)
{
    const int l = (int)threadIdx.x & 63;
    const int w = (int)threadIdx.x >> 6;

    // staging: wave w rows [w*32, w*32+32): lane -> row w*32+(l>>2), slot l&3
    const int srcswz = 8 * ((l & 3) ^ ((l >> 3) & 3));
    const u16* pA = A + (long)(rowA0 + w * 32 + (l >> 2)) * lda + srcswz;
    const u16* pB = B + (long)(rowB0 + w * 32 + (l >> 2)) * ldb + srcswz;
    const int dstb = w * 1024 + l * 8;

    // fragment read constants (swizzle folds per-lane)
    const int swz = (l >> 1) & 3;
    const int hi  = l >> 5;
    const int s0  = 8 * (hi ^ swz);          // k-slot, even ks within half
    const int s1  = 8 * ((2 + hi) ^ swz);    // odd ks within half
    const int RA  = (wm * 128 + (l & 31)) * 32;
    const int RB  = (wn * 64  + (l & 31)) * 32;

    bf16x8 af0[4][2], bf0[2][2], af1[4][2], bf1[2][2];

#define STG(tile, kh)                                                          \
    {                                                                          \
        const long co = (long)(tile) * 64 + (kh) * 32;                         \
        u16* d = lds + (((tile) & 1) << 15) + ((kh) << 13) + dstb;             \
        gload_lds16(pA + co, d);                                               \
        gload_lds16(pA + co + 16 * (long)lda, d + 512);                        \
        gload_lds16(pB + co, d + 16384);                                       \
        gload_lds16(pB + co + 16 * (long)ldb, d + 16384 + 512);                \
    }

#define RD_SET(af, bfr, tile, ksh)                                             \
    {                                                                          \
        const u16* base = lds + (((tile) & 1) << 15) + ((ksh) << 13);          \
        _Pragma("unroll")                                                      \
        for (int mi = 0; mi < 4; mi++) {                                       \
            af[mi][0] = *(const bf16x8*)(base + RA + mi * 1024 + s0);          \
            af[mi][1] = *(const bf16x8*)(base + RA + mi * 1024 + s1);          \
        }                                                                      \
        _Pragma("unroll")                                                      \
        for (int ni = 0; ni < 2; ni++) {                                       \
            bfr[ni][0] = *(const bf16x8*)(base + 16384 + RB + ni * 1024 + s0); \
            bfr[ni][1] = *(const bf16x8*)(base + 16384 + RB + ni * 1024 + s1); \
        }                                                                      \
    }

#define MF8(a_, b_, milo)                                                      \
    {                                                                          \
        __builtin_amdgcn_s_setprio(1);                                         \
        _Pragma("unroll")                                                      \
        for (int mi = (milo); mi < (milo) + 2; mi++)                           \
            _Pragma("unroll")                                                  \
            for (int ni = 0; ni < 2; ni++)                                     \
                _Pragma("unroll")                                              \
                for (int kb = 0; kb < 2; kb++)                                 \
                    acc[mi][ni] = __builtin_amdgcn_mfma_f32_32x32x16_bf16(     \
                        a_[mi][kb], b_[ni][kb], acc[mi][ni], 0, 0, 0);         \
        __builtin_amdgcn_s_setprio(0);                                         \
    }
#define BAR()  __builtin_amdgcn_s_barrier()
#define LGKM0()                                                                \
    {                                                                          \
        asm volatile("s_waitcnt lgkmcnt(0)" ::: "memory");                     \
        __builtin_amdgcn_sched_barrier(0);                                     \
    }

    // ---- prologue: stage tiles 0,1; read set0 = (tile0, K-half0) ----
    STG(0, 0); STG(0, 1); STG(1, 0); STG(1, 1);
    asm volatile("s_waitcnt vmcnt(8)" ::: "memory");  // tile0 resident
    BAR();
    RD_SET(af0, bf0, 0, 0);
    LGKM0();
    BAR();   // all waves done reading before later stages can land here

    for (int t = 0; t < T; ++t) {
        const int ts  = (t + 2 < T) ? t + 2 : T - 1;  // clamp: dead rewrite
        const int t1c = (t + 1 < T) ? t + 1 : T - 1;

        // ph1: read K-half1 frags of tile t; MFMA set0 mi0-1
        RD_SET(af1, bf1, t, 1);
        MF8(af0, bf0, 0);

        // ph2: stage kh0(t+2); MFMA set0 mi2-3; drain reads; vmcnt pre-bar
        STG(ts, 0);
        MF8(af0, bf0, 2);
        LGKM0();
        asm volatile("s_waitcnt vmcnt(4)" ::: "memory");
        BAR();

        // ph3: read K-half0 frags of tile t+1; MFMA set1 mi0-1
        RD_SET(af0, bf0, t1c, 0);
        MF8(af1, bf1, 0);

        // ph4: stage kh1(t+2); MFMA set1 mi2-3; drain reads
        STG(ts, 1);
        MF8(af1, bf1, 2);
        LGKM0();
        BAR();
    }
    asm volatile("s_waitcnt vmcnt(0)" ::: "memory");  // drain tail stages

#undef STG
#undef RD_SET
#undef MF8
#undef BAR
#undef LGKM0
}

// ---------------------------------------------------------------------------
// Kernel 1: fp32 -> bf16 casts
// ---------------------------------------------------------------------------
__global__ __launch_bounds__(256)
void cast6(const float* __restrict__ q, const float* __restrict__ k,
           const float* __restrict__ v, const float* __restrict__ wq,
           const float* __restrict__ wk, const float* __restrict__ wv,
           u16* __restrict__ qb, u16* __restrict__ kb, u16* __restrict__ vb,
           u16* __restrict__ wqb, u16* __restrict__ wkb, u16* __restrict__ wvb,
           int nqkv, int nw)
{
    const int z = blockIdx.y;
    const float* s; u16* d; int n;
    switch (z) {
        case 0:  s = q;  d = qb;  n = nqkv; break;
        case 1:  s = k;  d = kb;  n = nqkv; break;
        case 2:  s = v;  d = vb;  n = nqkv; break;
        case 3:  s = wq; d = wqb; n = nw;   break;
        case 4:  s = wk; d = wkb; n = nw;   break;
        default: s = wv; d = wvb; n = nw;   break;
    }
    long i = ((long)blockIdx.x * 256 + threadIdx.x) * 8;
    if (i >= n) return;
    float4 a = *(const float4*)(s + i);
    float4 b = *(const float4*)(s + i + 4);
    ushort4 o0, o1;
    o0.x = f2bf(a.x); o0.y = f2bf(a.y); o0.z = f2bf(a.z); o0.w = f2bf(a.w);
    o1.x = f2bf(b.x); o1.y = f2bf(b.y); o1.z = f2bf(b.z); o1.w = f2bf(b.w);
    *(ushort4*)(d + i)     = o0;
    *(ushort4*)(d + i + 4) = o1;
}

// ---------------------------------------------------------------------------
// Kernel 2: all three projections in one launch, grid (8, 32, 3):
//   z=0: qp = (q @ Wq^T + bq)*scale        (OUT rows = tokens)
//   z=1: kp = k @ Wk^T + bk                (OUT rows = tokens)
//   z=2: vpT = Wv @ v^T + bv, coalesced    (bm=bx over features, bn=by tokens)
// ---------------------------------------------------------------------------
__global__ __launch_bounds__(256, 2)
void proj_gemm(const u16* __restrict__ qb, const u16* __restrict__ kb,
               const u16* __restrict__ vb, const u16* __restrict__ wqb,
               const u16* __restrict__ wkb, const u16* __restrict__ wvb,
               const float* __restrict__ bq, const float* __restrict__ bk,
               const float* __restrict__ bv,
               u16* __restrict__ qp, u16* __restrict__ kp, u16* __restrict__ vpT)
{
    __shared__ __align__(16) u16 sA[8192];
    __shared__ __align__(16) u16 sB[8192];
    int bx, by, bz;
    xcd_swz(8, 32, bx, by, bz);
    const int z = bz;

    f32x4 acc[4][4] = {};
    const int lane = threadIdx.x & 63;
    const int wm   = (threadIdx.x >> 7) & 1;
    const int wn   = (threadIdx.x >> 6) & 1;

    if (z == 2) {
        // vpT = Wv @ v^T: A=Wv rows (features, M=1024 via bx), B=v rows (tokens)
        gemm_core(wvb, vb, 1024, 1024, 1024, bx, by, sA, sB, acc);
        const int m0 = bx * 128 + wm * 64 + ((lane >> 4) << 2);
        const int n0 = by * 128 + wn * 64 + (lane & 15);
#pragma unroll
        for (int mi = 0; mi < 4; mi++)
#pragma unroll
            for (int ni = 0; ni < 4; ni++) {
                const int gm = m0 + mi * 16;
                const int gn = n0 + ni * 16;
#pragma unroll
                for (int r = 0; r < 4; r++)
                    vpT[(long)(gm + r) * 4096 + gn] = f2bf(acc[mi][ni][r] + bv[gm + r]);
            }
        return;
    }

    const u16* A = (z == 0) ? qb : kb;
    const u16* B = (z == 0) ? wqb : wkb;
    const float* bias = (z == 0) ? bq : bk;
    u16* OUT = (z == 0) ? qp : kp;
    const float scale = (z == 0) ? 0.03125f : 1.0f;  // 1024^-0.5

    gemm_core(A, B, 1024, 1024, 1024, by, bx, sA, sB, acc);

    const int m0 = by * 128 + wm * 64 + ((lane >> 4) << 2);
    const int n0 = bx * 128 + wn * 64 + (lane & 15);
#pragma unroll
    for (int mi = 0; mi < 4; mi++)
#pragma unroll
        for (int ni = 0; ni < 4; ni++) {
            const int gm = m0 + mi * 16;
            const int gn = n0 + ni * 16;
            const float bb = bias[gn];
#pragma unroll
            for (int r = 0; r < 4; r++)
                OUT[(long)(gm + r) * 1024 + gn] = f2bf((acc[mi][ni][r] + bb) * scale);
        }
}

// ---------------------------------------------------------------------------
// Kernel 3: scores = qp @ kp^T -> bf16 S. 256x256 core, 32x32x16 MFMA.
// ---------------------------------------------------------------------------
__global__ __launch_bounds__(512, 2)
void score_gemm256(const u16* __restrict__ qp, const u16* __restrict__ kp,
                   u16* __restrict__ S)
{
    __shared__ __align__(16) u16 lds[65536];  // 128 KB

    const int flat = (int)blockIdx.x + ((int)blockIdx.y << 4);
    const int sfl = (flat & 7) * 32 + (flat >> 3);
    const int bx = sfl & 15;   // N tile
    const int by = sfl >> 4;   // M tile

    const int l  = (int)threadIdx.x & 63;
    const int w  = (int)threadIdx.x >> 6;
    const int wm = w >> 2;
    const int wn = w & 3;

    f32x16 acc[4][2] = {};
    gemm256_core(qp, kp, 1024, 1024, 16, by * 256, bx * 256, lds, acc, wm, wn);

    const int hi = l >> 5;
    const int gm0 = by * 256 + wm * 128 + 4 * hi;
    const int gn0 = bx * 256 + wn * 64 + (l & 31);
#pragma unroll
    for (int mi = 0; mi < 4; mi++)
#pragma unroll
        for (int ni = 0; ni < 2; ni++) {
            const int gmb = gm0 + mi * 32;
            const int gn  = gn0 + ni * 32;
#pragma unroll
            for (int r = 0; r < 16; r++) {
                const int row = gmb + (r & 3) + 8 * (r >> 2);
                S[(long)row * 4096 + gn] = f2bf(acc[mi][ni][r]);
            }
        }
}

// ---------------------------------------------------------------------------
// Kernel 4: att = softmax(S_bf16, axis=-1) + bias, cast to bf16. Block per row.
// ---------------------------------------------------------------------------
__global__ __launch_bounds__(256)
void softmax_bias(const u16* __restrict__ S, const float* __restrict__ bias,
                  u16* __restrict__ att)
{
    const long row = blockIdx.x;
    const int tid = threadIdx.x;
    const u16* srow = S + row * 4096 + tid * 16;

    float v[16];
    {
        uint4 a = *(const uint4*)(srow);
        uint4 b = *(const uint4*)(srow + 8);
        unsigned w[8] = {a.x, a.y, a.z, a.w, b.x, b.y, b.z, b.w};
#pragma unroll
        for (int i = 0; i < 8; i++) {
            v[2 * i]     = bf2f(w[i] << 16);
            v[2 * i + 1] = bf2f(w[i] & 0xffff0000u);
        }
    }
    float mx = v[0];
#pragma unroll
    for (int i = 1; i < 16; i++) mx = fmaxf(mx, v[i]);
#pragma unroll
    for (int o = 32; o >= 1; o >>= 1) mx = fmaxf(mx, __shfl_xor(mx, o, 64));
    __shared__ float red[8];
    if ((tid & 63) == 0) red[tid >> 6] = mx;
    __syncthreads();
    mx = fmaxf(fmaxf(red[0], red[1]), fmaxf(red[2], red[3]));
    float sum = 0.f;
#pragma unroll
    for (int i = 0; i < 16; i++) { v[i] = __expf(v[i] - mx); sum += v[i]; }
#pragma unroll
    for (int o = 32; o >= 1; o >>= 1) sum += __shfl_xor(sum, o, 64);
    if ((tid & 63) == 0) red[4 + (tid >> 6)] = sum;
    __syncthreads();
    const float inv = 1.0f / (red[4] + red[5] + red[6] + red[7]);

    const float4* brow = (const float4*)(bias + row * 4096 + tid * 16);
    unsigned o[8];
#pragma unroll
    for (int i = 0; i < 4; i++) {
        float4 b = brow[i];
        unsigned lo = f2bf(v[4 * i + 0] * inv + b.x);
        unsigned hi = f2bf(v[4 * i + 1] * inv + b.y);
        o[2 * i] = lo | (hi << 16);
        lo = f2bf(v[4 * i + 2] * inv + b.z);
        hi = f2bf(v[4 * i + 3] * inv + b.w);
        o[2 * i + 1] = lo | (hi << 16);
    }
    u16* arow = att + row * 4096 + tid * 16;
    *(uint4*)(arow)     = make_uint4(o[0], o[1], o[2], o[3]);
    *(uint4*)(arow + 8) = make_uint4(o[4], o[5], o[6], o[7]);
}

// ---------------------------------------------------------------------------
// Kernel 5: split-K=4: P[z] = att[:, z*1024..] @ vpT[:, z*1024..]^T, fp32.
// 256x256 core, 32x32x16 MFMA. Grid (4, 16, 4) = 256 blocks.
// ---------------------------------------------------------------------------
__global__ __launch_bounds__(512, 2)
void out_gemm256(const u16* __restrict__ att, const u16* __restrict__ vpT,
                 float* __restrict__ P)
{
    __shared__ __align__(16) u16 lds[65536];  // 128 KB

    int bx, by, bz;
    xcd_swz(4, 16, bx, by, bz);
    const u16* A = att + bz * 1024;
    const u16* B = vpT + bz * 1024;
    float* O = P + (long)bz * 4096 * 1024;

    const int l  = (int)threadIdx.x & 63;
    const int w  = (int)threadIdx.x >> 6;
    const int wm = w >> 2;
    const int wn = w & 3;

    f32x16 acc[4][2] = {};
    gemm256_core(A, B, 4096, 4096, 16, by * 256, bx * 256, lds, acc, wm, wn);

    const int hi = l >> 5;
    const int gm0 = by * 256 + wm * 128 + 4 * hi;
    const int gn0 = bx * 256 + wn * 64 + (l & 31);
#pragma unroll
    for (int mi = 0; mi < 4; mi++)
#pragma unroll
        for (int ni = 0; ni < 2; ni++) {
            const int gmb = gm0 + mi * 32;
            const int gn  = gn0 + ni * 32;
#pragma unroll
            for (int r = 0; r < 16; r++) {
                const int row = gmb + (r & 3) + 8 * (r >> 2);
                O[(long)row * 1024 + gn] = acc[mi][ni][r];
            }
        }
}

// ---------------------------------------------------------------------------
// Kernel 6: out = P0 + P1 + P2 + P3  (fp32), 4096x1024
// ---------------------------------------------------------------------------
__global__ __launch_bounds__(256)
void addp4(const float* __restrict__ P, float* __restrict__ O)
{
    long i = ((long)blockIdx.x * 256 + threadIdx.x) * 4;
    const long st = 4194304;
    float4 a = *(const float4*)(P + i);
    float4 b = *(const float4*)(P + st + i);
    float4 c = *(const float4*)(P + 2 * st + i);
    float4 d = *(const float4*)(P + 3 * st + i);
    float4 r;
    r.x = (a.x + b.x) + (c.x + d.x);
    r.y = (a.y + b.y) + (c.y + d.y);
    r.z = (a.z + b.z) + (c.z + d.z);
    r.w = (a.w + b.w) + (c.w + d.w);
    *(float4*)(O + i) = r;
}

// ---------------------------------------------------------------------------
extern "C" void kernel_launch(void* const* d_in, const int* in_sizes, int n_in,
                              void* d_out, int out_size, void* d_ws, size_t ws_size,
                              hipStream_t stream)
{
    const float* q    = (const float*)d_in[0];
    const float* k    = (const float*)d_in[1];
    const float* v    = (const float*)d_in[2];
    const float* bias = (const float*)d_in[3];
    const float* Wq   = (const float*)d_in[4];
    const float* bq   = (const float*)d_in[5];
    const float* Wk   = (const float*)d_in[6];
    const float* bk   = (const float*)d_in[7];
    const float* Wv   = (const float*)d_in[8];
    const float* bv   = (const float*)d_in[9];
    float* out = (float*)d_out;

    uint8_t* ws = (uint8_t*)d_ws;
    const size_t MB = 1u << 20;
    // layout (118 MB):
    //   [0,8)    qb   [8,16) kb   [16,24) vb        (dead after proj)
    //   [24,26)  wqb  [26,28) wkb [28,30) wvb       (dead after proj)
    //   [30,38)  qp   [38,46) kp                    (dead after score)
    //   [46,54)  vpT
    //   [54,86)  S (bf16 scores, 32MB)              (dead after softmax)
    //   [0,32)   att (bf16, 32MB) -- aliases dead qb/kb/vb region
    //   [54,118) P (4x fp32 partials, 16MB each) -- aliases dead S
    u16* qb  = (u16*)(ws);
    u16* kb  = (u16*)(ws + 8 * MB);
    u16* vb  = (u16*)(ws + 16 * MB);
    u16* wqb = (u16*)(ws + 24 * MB);
    u16* wkb = (u16*)(ws + 26 * MB);
    u16* wvb = (u16*)(ws + 28 * MB);
    u16* qp  = (u16*)(ws + 30 * MB);
    u16* kp  = (u16*)(ws + 38 * MB);
    u16* vpT = (u16*)(ws + 46 * MB);
    u16* S   = (u16*)(ws + 54 * MB);
    u16* att = (u16*)(ws);
    float* P = (float*)(ws + 54 * MB);

    cast6<<<dim3(2048, 6), 256, 0, stream>>>(q, k, v, Wq, Wk, Wv,
                                             qb, kb, vb, wqb, wkb, wvb,
                                             4096 * 1024, 1024 * 1024);
    proj_gemm<<<dim3(8, 32, 3), 256, 0, stream>>>(qb, kb, vb, wqb, wkb, wvb,
                                                  bq, bk, bv, qp, kp, vpT);
    score_gemm256<<<dim3(16, 16), 512, 0, stream>>>(qp, kp, S);
    softmax_bias<<<dim3(4096), 256, 0, stream>>>(S, bias, att);
    out_gemm256<<<dim3(4, 16, 4), 512, 0, stream>>>(att, vpT, P);
    addp4<<<dim3(4096), 256, 0, stream>>>(P, out);
}

// Round 7
// 290.099 us; speedup vs baseline: 1.0435x; 1.0216x over previous
//
#include <hip/hip_runtime.h>
#include <hip/hip_bf16.h>
#include <stdint.h>

typedef unsigned short u16;
using bf16x8 = __attribute__((ext_vector_type(8))) __bf16;
using f32x4  = __attribute__((ext_vector_type(4))) float;

// fp32 -> bf16 (round-to-nearest-even), as raw bits
__device__ __forceinline__ u16 f2bf(float f) {
    union { float f; unsigned u; } a; a.f = f;
    unsigned u = a.u;
    u += 0x7fffu + ((u >> 16) & 1u);
    return (u16)(u >> 16);
}
__device__ __forceinline__ float bf2f(unsigned bits_hi16) {
    union { unsigned u; float f; } a; a.u = bits_hi16; return a.f;
}

// async global->LDS, 16 bytes per lane (global_load_lds_dwordx4)
__device__ __forceinline__ void gload_lds16(const void* g, void* l) {
    __builtin_amdgcn_global_load_lds(
        (const __attribute__((address_space(1))) void*)g,
        (__attribute__((address_space(3))) void*)l, 16, 0, 0);
}

// Bijective XCD-aware swizzle (T1); requires nwg % 8 == 0.
__device__ __forceinline__ void xcd_swz(int nx, int ny, int& x, int& y, int& z) {
    const int flat = (int)blockIdx.x + nx * ((int)blockIdx.y + ny * (int)blockIdx.z);
    const int cpx = (nx * ny * (int)gridDim.z) >> 3;  // chunk per XCD
    const int s = (flat & 7) * cpx + (flat >> 3);
    x = s % nx;
    const int t = s / nx;
    y = t % ny;
    z = t / ny;
}

// ---------------------------------------------------------------------------
// Legacy 128x128-tile bf16 GEMM core (m97 structure), C = A @ B^T.
// Used by proj (QKV projections).
// ---------------------------------------------------------------------------
__device__ __forceinline__ void gemm_core(const u16* __restrict__ A,
                                          const u16* __restrict__ B,
                                          int lda, int ldb, int kLen,
                                          int bm, int bn,
                                          u16* sA, u16* sB,
                                          f32x4 acc[4][4])
{
    const int tid  = threadIdx.x;
    const int lane = tid & 63;
    const int wm   = (tid >> 7) & 1;
    const int wn   = (tid >> 6) & 1;

    const u16* Ag0 = A + (long)(bm * 128 + (tid >> 2)) * lda + (tid & 3) * 8;
    const u16* Ag1 = Ag0 + (long)64 * lda;
    const u16* Bg0 = B + (long)(bn * 128 + (tid >> 2)) * ldb + (tid & 3) * 8;
    const u16* Bg1 = Bg0 + (long)64 * ldb;
    u16* la = sA + tid * 8;
    u16* lb = sB + tid * 8;

    const int rfo  = (wm * 64 + (lane & 15)) * 32 + (lane >> 4) * 8;
    const int rfoB = (wn * 64 + (lane & 15)) * 32 + (lane >> 4) * 8;

    for (int k0 = 0; k0 < kLen; k0 += 64) {
        gload_lds16(Ag0 + k0, la);
        gload_lds16(Ag1 + k0, la + 2048);
        gload_lds16(Bg0 + k0, lb);
        gload_lds16(Bg1 + k0, lb + 2048);
        gload_lds16(Ag0 + k0 + 32, la + 4096);
        gload_lds16(Ag1 + k0 + 32, la + 6144);
        gload_lds16(Bg0 + k0 + 32, lb + 4096);
        gload_lds16(Bg1 + k0 + 32, lb + 6144);
        __syncthreads();
#pragma unroll
        for (int h = 0; h < 2; h++) {
            const u16* ra = sA + h * 4096 + rfo;
            const u16* rb = sB + h * 4096 + rfoB;
            bf16x8 af[4], bfr[4];
#pragma unroll
            for (int i = 0; i < 4; i++) af[i]  = *(const bf16x8*)(ra + i * 512);
#pragma unroll
            for (int i = 0; i < 4; i++) bfr[i] = *(const bf16x8*)(rb + i * 512);
#pragma unroll
            for (int mi = 0; mi < 4; mi++)
#pragma unroll
                for (int ni = 0; ni < 4; ni++)
                    acc[mi][ni] = __builtin_amdgcn_mfma_f32_16x16x32_bf16(
                        af[mi], bfr[ni], acc[mi][ni], 0, 0, 0);
        }
        __syncthreads();
    }
}

// ---------------------------------------------------------------------------
// 256x256-tile, 8-wave, register-double-buffered pipelined GEMM core,
// 16x16x32 MFMA (R3-measured best: 0 bank conflicts, out=40.9us).
// C = A @ B^T over K = T*64.
//
// LDS 128 KB: 2 tile-buffers x { A:[2 kh][256 r][32 c] u16, B: same @+16384 }.
// Bank swizzle: LDS[r][slot16] = G[r][slot16 ^ ((r>>1)&3)] via pre-swizzled
// global source (gload_lds dest linear); read-side XOR folds per-lane.
//
// Pipeline per K-tile t (buf b=t&1; frag set0=ks0, set1=ks1):
//  ph1: ds_read set1 <- (t,ks1)        ; MFMA mi0-3 ks0 (set0)
//  ph2: stage kh0(t+2)->buf b          ; MFMA mi4-7 ks0 ; lgkm(0);
//       vmcnt(4) PRE-barrier           ; barrier
//  ph3: ds_read set0 <- (t+1,ks0)      ; MFMA mi0-3 ks1
//  ph4: stage kh1(t+2)->buf b          ; MFMA mi4-7 ks1 ; lgkm(0); barrier
// vmcnt(4) pre-barrier retires exactly tile t+1's 8 loads (count audit:
// steady-state outstanding at that point = 12), and because every wave
// waits BEFORE crossing the barrier, tile t+1 residency composes
// block-wide (fixes R3's per-wave-only guarantee).
// lgkm(0)+barrier at ph2/ph4 = exact cross-wave guard before overwrite.
// Tail: stage clamps to T-1 (benign same-byte rewrite) keeping counts
// uniform for every t.
// ---------------------------------------------------------------------------
__device__ __forceinline__ void gemm256_core(const u16* __restrict__ A,
                                             const u16* __restrict__ B,
                                             int lda, int ldb, int T,
                                             int rowA0, int rowB0,
                                             u16* lds,
                                             f32x4 acc[8][4],
                                             int wm, int wn)
{
    const int l = (int)threadIdx.x & 63;
    const int w = (int)threadIdx.x >> 6;

    // staging: wave w rows [w*32, w*32+32): lane -> row w*32+(l>>2), slot l&3
    const int srcswz = 8 * ((l & 3) ^ ((l >> 3) & 3));
    const u16* pA = A + (long)(rowA0 + w * 32 + (l >> 2)) * lda + srcswz;
    const u16* pB = B + (long)(rowB0 + w * 32 + (l >> 2)) * ldb + srcswz;
    const int dstbase = w * 1024 + l * 8;

    // fragment read bases (swizzle constant per lane)
    const int fsw = 8 * ((l >> 4) ^ ((l >> 1) & 3));
    const int fA = (wm * 128 + (l & 15)) * 32 + fsw;
    const int fB = (wn * 64  + (l & 15)) * 32 + fsw;

    bf16x8 af0[8], bf0[4], af1[8], bf1[4];

#define STAGE(tile, kh)                                                        \
    {                                                                          \
        const long co = (long)(tile) * 64 + (kh) * 32;                         \
        u16* d = lds + (((tile) & 1) << 15) + ((kh) << 13) + dstbase;          \
        gload_lds16(pA + co, d);                                               \
        gload_lds16(pA + co + 16 * (long)lda, d + 512);                        \
        gload_lds16(pB + co, d + 16384);                                       \
        gload_lds16(pB + co + 16 * (long)ldb, d + 16384 + 512);                \
    }

#define RD(af, bfr, tile, ks)                                                  \
    {                                                                          \
        const u16* Ar = lds + (((tile) & 1) << 15) + ((ks) << 13);             \
        const u16* Br = Ar + 16384;                                            \
        _Pragma("unroll")                                                      \
        for (int mi = 0; mi < 8; mi++)                                         \
            af[mi] = *(const bf16x8*)(Ar + fA + mi * 512);                     \
        _Pragma("unroll")                                                      \
        for (int ni = 0; ni < 4; ni++)                                         \
            bfr[ni] = *(const bf16x8*)(Br + fB + ni * 512);                    \
    }

#define MF(af, bfr, lo)                                                        \
    {                                                                          \
        __builtin_amdgcn_s_setprio(1);                                         \
        _Pragma("unroll")                                                      \
        for (int mi = (lo); mi < (lo) + 4; mi++)                               \
            _Pragma("unroll")                                                  \
            for (int ni = 0; ni < 4; ni++)                                     \
                acc[mi][ni] = __builtin_amdgcn_mfma_f32_16x16x32_bf16(         \
                    af[mi], bfr[ni], acc[mi][ni], 0, 0, 0);                    \
        __builtin_amdgcn_s_setprio(0);                                         \
    }

    // ---- prologue: stage tiles 0,1; read set0 = (0, ks0) ----
    STAGE(0, 0); STAGE(0, 1); STAGE(1, 0); STAGE(1, 1);
    asm volatile("s_waitcnt vmcnt(8)" ::: "memory");  // tile0 resident
    __builtin_amdgcn_s_barrier();
    RD(af0, bf0, 0, 0);
    asm volatile("s_waitcnt lgkmcnt(0)" ::: "memory");
    __builtin_amdgcn_s_barrier();   // all waves done reading before stages land

    for (int t = 0; t < T; ++t) {
        const int t2  = (t + 2 < T) ? t + 2 : T - 1;   // clamp: same-byte rewrite
        const int t1c = (t + 1 < T) ? t + 1 : T - 1;

        // ph1: read ks1 frags; MFMA ks0 lo
        RD(af1, bf1, t, 1);
        MF(af0, bf0, 0);

        // ph2: stage kh0(t2); MFMA ks0 hi; guard overwrite; tile t+1 residency
        STAGE(t2, 0);
        MF(af0, bf0, 4);
        asm volatile("s_waitcnt lgkmcnt(0) vmcnt(4)" ::: "memory");
        __builtin_amdgcn_s_barrier();

        // ph3: read (t+1, ks0) frags [resident block-wide]; MFMA ks1 lo
        RD(af0, bf0, t1c, 0);
        MF(af1, bf1, 0);

        // ph4: stage kh1(t2); MFMA ks1 hi; guard next overwrite
        STAGE(t2, 1);
        MF(af1, bf1, 4);
        asm volatile("s_waitcnt lgkmcnt(0)" ::: "memory");
        __builtin_amdgcn_s_barrier();
    }
    asm volatile("s_waitcnt vmcnt(0)" ::: "memory");  // drain tail stages

#undef STAGE
#undef RD
#undef MF
}

// ---------------------------------------------------------------------------
// Kernel 1: fp32 -> bf16 casts
// ---------------------------------------------------------------------------
__global__ __launch_bounds__(256)
void cast6(const float* __restrict__ q, const float* __restrict__ k,
           const float* __restrict__ v, const float* __restrict__ wq,
           const float* __restrict__ wk, const float* __restrict__ wv,
           u16* __restrict__ qb, u16* __restrict__ kb, u16* __restrict__ vb,
           u16* __restrict__ wqb, u16* __restrict__ wkb, u16* __restrict__ wvb,
           int nqkv, int nw)
{
    const int z = blockIdx.y;
    const float* s; u16* d; int n;
    switch (z) {
        case 0:  s = q;  d = qb;  n = nqkv; break;
        case 1:  s = k;  d = kb;  n = nqkv; break;
        case 2:  s = v;  d = vb;  n = nqkv; break;
        case 3:  s = wq; d = wqb; n = nw;   break;
        case 4:  s = wk; d = wkb; n = nw;   break;
        default: s = wv; d = wvb; n = nw;   break;
    }
    long i = ((long)blockIdx.x * 256 + threadIdx.x) * 8;
    if (i >= n) return;
    float4 a = *(const float4*)(s + i);
    float4 b = *(const float4*)(s + i + 4);
    ushort4 o0, o1;
    o0.x = f2bf(a.x); o0.y = f2bf(a.y); o0.z = f2bf(a.z); o0.w = f2bf(a.w);
    o1.x = f2bf(b.x); o1.y = f2bf(b.y); o1.z = f2bf(b.z); o1.w = f2bf(b.w);
    *(ushort4*)(d + i)     = o0;
    *(ushort4*)(d + i + 4) = o1;
}

// ---------------------------------------------------------------------------
// Kernel 2: all three projections in one launch, grid (8, 32, 3):
//   z=0: qp = (q @ Wq^T + bq)*scale        (OUT rows = tokens)
//   z=1: kp = k @ Wk^T + bk                (OUT rows = tokens)
//   z=2: vpT = Wv @ v^T + bv, coalesced    (bm=bx over features, bn=by tokens)
// ---------------------------------------------------------------------------
__global__ __launch_bounds__(256, 2)
void proj_gemm(const u16* __restrict__ qb, const u16* __restrict__ kb,
               const u16* __restrict__ vb, const u16* __restrict__ wqb,
               const u16* __restrict__ wkb, const u16* __restrict__ wvb,
               const float* __restrict__ bq, const float* __restrict__ bk,
               const float* __restrict__ bv,
               u16* __restrict__ qp, u16* __restrict__ kp, u16* __restrict__ vpT)
{
    __shared__ __align__(16) u16 sA[8192];
    __shared__ __align__(16) u16 sB[8192];
    int bx, by, bz;
    xcd_swz(8, 32, bx, by, bz);
    const int z = bz;

    f32x4 acc[4][4] = {};
    const int lane = threadIdx.x & 63;
    const int wm   = (threadIdx.x >> 7) & 1;
    const int wn   = (threadIdx.x >> 6) & 1;

    if (z == 2) {
        // vpT = Wv @ v^T: A=Wv rows (features, M=1024 via bx), B=v rows (tokens)
        gemm_core(wvb, vb, 1024, 1024, 1024, bx, by, sA, sB, acc);
        const int m0 = bx * 128 + wm * 64 + ((lane >> 4) << 2);
        const int n0 = by * 128 + wn * 64 + (lane & 15);
#pragma unroll
        for (int mi = 0; mi < 4; mi++)
#pragma unroll
            for (int ni = 0; ni < 4; ni++) {
                const int gm = m0 + mi * 16;
                const int gn = n0 + ni * 16;
#pragma unroll
                for (int r = 0; r < 4; r++)
                    vpT[(long)(gm + r) * 4096 + gn] = f2bf(acc[mi][ni][r] + bv[gm + r]);
            }
        return;
    }

    const u16* A = (z == 0) ? qb : kb;
    const u16* B = (z == 0) ? wqb : wkb;
    const float* bias = (z == 0) ? bq : bk;
    u16* OUT = (z == 0) ? qp : kp;
    const float scale = (z == 0) ? 0.03125f : 1.0f;  // 1024^-0.5

    gemm_core(A, B, 1024, 1024, 1024, by, bx, sA, sB, acc);

    const int m0 = by * 128 + wm * 64 + ((lane >> 4) << 2);
    const int n0 = bx * 128 + wn * 64 + (lane & 15);
#pragma unroll
    for (int mi = 0; mi < 4; mi++)
#pragma unroll
        for (int ni = 0; ni < 4; ni++) {
            const int gm = m0 + mi * 16;
            const int gn = n0 + ni * 16;
            const float bb = bias[gn];
#pragma unroll
            for (int r = 0; r < 4; r++)
                OUT[(long)(gm + r) * 1024 + gn] = f2bf((acc[mi][ni][r] + bb) * scale);
        }
}

// ---------------------------------------------------------------------------
// Kernel 3: scores = qp @ kp^T -> bf16 S. 256x256 pipelined core (16x16x32).
// ---------------------------------------------------------------------------
__global__ __launch_bounds__(512, 2)
void score_gemm256(const u16* __restrict__ qp, const u16* __restrict__ kp,
                   u16* __restrict__ S)
{
    __shared__ __align__(16) u16 lds[65536];  // 128 KB

    const int flat = (int)blockIdx.x + ((int)blockIdx.y << 4);
    const int sfl = (flat & 7) * 32 + (flat >> 3);
    const int bx = sfl & 15;   // N tile
    const int by = sfl >> 4;   // M tile

    const int l  = (int)threadIdx.x & 63;
    const int w  = (int)threadIdx.x >> 6;
    const int wm = w >> 2;
    const int wn = w & 3;

    f32x4 acc[8][4] = {};
    gemm256_core(qp, kp, 1024, 1024, 16, by * 256, bx * 256, lds, acc, wm, wn);

    const int gm0 = by * 256 + wm * 128 + ((l >> 4) << 2);
    const int gn0 = bx * 256 + wn * 64 + (l & 15);
#pragma unroll
    for (int mi = 0; mi < 8; mi++)
#pragma unroll
        for (int ni = 0; ni < 4; ni++) {
            const int gm = gm0 + mi * 16;
            const int gn = gn0 + ni * 16;
#pragma unroll
            for (int r = 0; r < 4; r++)
                S[(long)(gm + r) * 4096 + gn] = f2bf(acc[mi][ni][r]);
        }
}

// ---------------------------------------------------------------------------
// Kernel 4: att = softmax(S_bf16, axis=-1) + bias, cast to bf16. Block per row.
// ---------------------------------------------------------------------------
__global__ __launch_bounds__(256)
void softmax_bias(const u16* __restrict__ S, const float* __restrict__ bias,
                  u16* __restrict__ att)
{
    const long row = blockIdx.x;
    const int tid = threadIdx.x;
    const u16* srow = S + row * 4096 + tid * 16;

    float v[16];
    {
        uint4 a = *(const uint4*)(srow);
        uint4 b = *(const uint4*)(srow + 8);
        unsigned w[8] = {a.x, a.y, a.z, a.w, b.x, b.y, b.z, b.w};
#pragma unroll
        for (int i = 0; i < 8; i++) {
            v[2 * i]     = bf2f(w[i] << 16);
            v[2 * i + 1] = bf2f(w[i] & 0xffff0000u);
        }
    }
    float mx = v[0];
#pragma unroll
    for (int i = 1; i < 16; i++) mx = fmaxf(mx, v[i]);
#pragma unroll
    for (int o = 32; o >= 1; o >>= 1) mx = fmaxf(mx, __shfl_xor(mx, o, 64));
    __shared__ float red[8];
    if ((tid & 63) == 0) red[tid >> 6] = mx;
    __syncthreads();
    mx = fmaxf(fmaxf(red[0], red[1]), fmaxf(red[2], red[3]));
    float sum = 0.f;
#pragma unroll
    for (int i = 0; i < 16; i++) { v[i] = __expf(v[i] - mx); sum += v[i]; }
#pragma unroll
    for (int o = 32; o >= 1; o >>= 1) sum += __shfl_xor(sum, o, 64);
    if ((tid & 63) == 0) red[4 + (tid >> 6)] = sum;
    __syncthreads();
    const float inv = 1.0f / (red[4] + red[5] + red[6] + red[7]);

    const float4* brow = (const float4*)(bias + row * 4096 + tid * 16);
    unsigned o[8];
#pragma unroll
    for (int i = 0; i < 4; i++) {
        float4 b = brow[i];
        unsigned lo = f2bf(v[4 * i + 0] * inv + b.x);
        unsigned hi = f2bf(v[4 * i + 1] * inv + b.y);
        o[2 * i] = lo | (hi << 16);
        lo = f2bf(v[4 * i + 2] * inv + b.z);
        hi = f2bf(v[4 * i + 3] * inv + b.w);
        o[2 * i + 1] = lo | (hi << 16);
    }
    u16* arow = att + row * 4096 + tid * 16;
    *(uint4*)(arow)     = make_uint4(o[0], o[1], o[2], o[3]);
    *(uint4*)(arow + 8) = make_uint4(o[4], o[5], o[6], o[7]);
}

// ---------------------------------------------------------------------------
// Kernel 5: split-K=4: P[z] = att[:, z*1024..] @ vpT[:, z*1024..]^T, fp32.
// 256x256 pipelined core (16x16x32). Grid (4, 16, 4) = 256 blocks, 1/CU.
// ---------------------------------------------------------------------------
__global__ __launch_bounds__(512, 2)
void out_gemm256(const u16* __restrict__ att, const u16* __restrict__ vpT,
                 float* __restrict__ P)
{
    __shared__ __align__(16) u16 lds[65536];  // 128 KB

    int bx, by, bz;
    xcd_swz(4, 16, bx, by, bz);
    const u16* A = att + bz * 1024;
    const u16* B = vpT + bz * 1024;
    float* O = P + (long)bz * 4096 * 1024;

    const int l  = (int)threadIdx.x & 63;
    const int w  = (int)threadIdx.x >> 6;
    const int wm = w >> 2;
    const int wn = w & 3;

    f32x4 acc[8][4] = {};
    gemm256_core(A, B, 4096, 4096, 16, by * 256, bx * 256, lds, acc, wm, wn);

    const int gm0 = by * 256 + wm * 128 + ((l >> 4) << 2);
    const int gn0 = bx * 256 + wn * 64 + (l & 15);
#pragma unroll
    for (int mi = 0; mi < 8; mi++)
#pragma unroll
        for (int ni = 0; ni < 4; ni++) {
            const int gm = gm0 + mi * 16;
            const int gn = gn0 + ni * 16;
#pragma unroll
            for (int r = 0; r < 4; r++)
                O[(long)(gm + r) * 1024 + gn] = acc[mi][ni][r];
        }
}

// ---------------------------------------------------------------------------
// Kernel 6: out = P0 + P1 + P2 + P3  (fp32), 4096x1024
// ---------------------------------------------------------------------------
__global__ __launch_bounds__(256)
void addp4(const float* __restrict__ P, float* __restrict__ O)
{
    long i = ((long)blockIdx.x * 256 + threadIdx.x) * 4;
    const long st = 4194304;
    float4 a = *(const float4*)(P + i);
    float4 b = *(const float4*)(P + st + i);
    float4 c = *(const float4*)(P + 2 * st + i);
    float4 d = *(const float4*)(P + 3 * st + i);
    float4 r;
    r.x = (a.x + b.x) + (c.x + d.x);
    r.y = (a.y + b.y) + (c.y + d.y);
    r.z = (a.z + b.z) + (c.z + d.z);
    r.w = (a.w + b.w) + (c.w + d.w);
    *(float4*)(O + i) = r;
}

// ---------------------------------------------------------------------------
extern "C" void kernel_launch(void* const* d_in, const int* in_sizes, int n_in,
                              void* d_out, int out_size, void* d_ws, size_t ws_size,
                              hipStream_t stream)
{
    const float* q    = (const float*)d_in[0];
    const float* k    = (const float*)d_in[1];
    const float* v    = (const float*)d_in[2];
    const float* bias = (const float*)d_in[3];
    const float* Wq   = (const float*)d_in[4];
    const float* bq   = (const float*)d_in[5];
    const float* Wk   = (const float*)d_in[6];
    const float* bk   = (const float*)d_in[7];
    const float* Wv   = (const float*)d_in[8];
    const float* bv   = (const float*)d_in[9];
    float* out = (float*)d_out;

    uint8_t* ws = (uint8_t*)d_ws;
    const size_t MB = 1u << 20;
    // layout (118 MB):
    //   [0,8)    qb   [8,16) kb   [16,24) vb        (dead after proj)
    //   [24,26)  wqb  [26,28) wkb [28,30) wvb       (dead after proj)
    //   [30,38)  qp   [38,46) kp                    (dead after score)
    //   [46,54)  vpT
    //   [54,86)  S (bf16 scores, 32MB)              (dead after softmax)
    //   [0,32)   att (bf16, 32MB) -- aliases dead qb/kb/vb region
    //   [54,118) P (4x fp32 partials, 16MB each) -- aliases dead S
    u16* qb  = (u16*)(ws);
    u16* kb  = (u16*)(ws + 8 * MB);
    u16* vb  = (u16*)(ws + 16 * MB);
    u16* wqb = (u16*)(ws + 24 * MB);
    u16* wkb = (u16*)(ws + 26 * MB);
    u16* wvb = (u16*)(ws + 28 * MB);
    u16* qp  = (u16*)(ws + 30 * MB);
    u16* kp  = (u16*)(ws + 38 * MB);
    u16* vpT = (u16*)(ws + 46 * MB);
    u16* S   = (u16*)(ws + 54 * MB);
    u16* att = (u16*)(ws);
    float* P = (float*)(ws + 54 * MB);

    cast6<<<dim3(2048, 6), 256, 0, stream>>>(q, k, v, Wq, Wk, Wv,
                                             qb, kb, vb, wqb, wkb, wvb,
                                             4096 * 1024, 1024 * 1024);
    proj_gemm<<<dim3(8, 32, 3), 256, 0, stream>>>(qb, kb, vb, wqb, wkb, wvb,
                                                  bq, bk, bv, qp, kp, vpT);
    score_gemm256<<<dim3(16, 16), 512, 0, stream>>>(qp, kp, S);
    softmax_bias<<<dim3(4096), 256, 0, stream>>>(S, bias, att);
    out_gemm256<<<dim3(4, 16, 4), 512, 0, stream>>>(att, vpT, P);
    addp4<<<dim3(4096), 256, 0, stream>>>(P, out);
}

// Round 8
// 286.237 us; speedup vs baseline: 1.0576x; 1.0135x over previous
//
#include <hip/hip_runtime.h>
#include <hip/hip_bf16.h>
#include <stdint.h>

typedef unsigned short u16;
using bf16x8 = __attribute__((ext_vector_type(8))) __bf16;
using f32x4  = __attribute__((ext_vector_type(4))) float;

// fp32 -> bf16 (round-to-nearest-even), as raw bits
__device__ __forceinline__ u16 f2bf(float f) {
    union { float f; unsigned u; } a; a.f = f;
    unsigned u = a.u;
    u += 0x7fffu + ((u >> 16) & 1u);
    return (u16)(u >> 16);
}
__device__ __forceinline__ float bf2f(unsigned bits_hi16) {
    union { unsigned u; float f; } a; a.u = bits_hi16; return a.f;
}

// async global->LDS, 16 bytes per lane (global_load_lds_dwordx4)
__device__ __forceinline__ void gload_lds16(const void* g, void* l) {
    __builtin_amdgcn_global_load_lds(
        (const __attribute__((address_space(1))) void*)g,
        (__attribute__((address_space(3))) void*)l, 16, 0, 0);
}

// Bijective XCD-aware swizzle (T1); requires nwg % 8 == 0.
__device__ __forceinline__ void xcd_swz(int nx, int ny, int& x, int& y, int& z) {
    const int flat = (int)blockIdx.x + nx * ((int)blockIdx.y + ny * (int)blockIdx.z);
    const int cpx = (nx * ny * (int)gridDim.z) >> 3;  // chunk per XCD
    const int s = (flat & 7) * cpx + (flat >> 3);
    x = s % nx;
    const int t = s / nx;
    y = t % ny;
    z = t / ny;
}

// ---------------------------------------------------------------------------
// Legacy 128x128-tile bf16 GEMM core (m97 structure), C = A @ B^T.
// Used by proj (QKV projections).
// ---------------------------------------------------------------------------
__device__ __forceinline__ void gemm_core(const u16* __restrict__ A,
                                          const u16* __restrict__ B,
                                          int lda, int ldb, int kLen,
                                          int bm, int bn,
                                          u16* sA, u16* sB,
                                          f32x4 acc[4][4])
{
    const int tid  = threadIdx.x;
    const int lane = tid & 63;
    const int wm   = (tid >> 7) & 1;
    const int wn   = (tid >> 6) & 1;

    const u16* Ag0 = A + (long)(bm * 128 + (tid >> 2)) * lda + (tid & 3) * 8;
    const u16* Ag1 = Ag0 + (long)64 * lda;
    const u16* Bg0 = B + (long)(bn * 128 + (tid >> 2)) * ldb + (tid & 3) * 8;
    const u16* Bg1 = Bg0 + (long)64 * ldb;
    u16* la = sA + tid * 8;
    u16* lb = sB + tid * 8;

    const int rfo  = (wm * 64 + (lane & 15)) * 32 + (lane >> 4) * 8;
    const int rfoB = (wn * 64 + (lane & 15)) * 32 + (lane >> 4) * 8;

    for (int k0 = 0; k0 < kLen; k0 += 64) {
        gload_lds16(Ag0 + k0, la);
        gload_lds16(Ag1 + k0, la + 2048);
        gload_lds16(Bg0 + k0, lb);
        gload_lds16(Bg1 + k0, lb + 2048);
        gload_lds16(Ag0 + k0 + 32, la + 4096);
        gload_lds16(Ag1 + k0 + 32, la + 6144);
        gload_lds16(Bg0 + k0 + 32, lb + 4096);
        gload_lds16(Bg1 + k0 + 32, lb + 6144);
        __syncthreads();
#pragma unroll
        for (int h = 0; h < 2; h++) {
            const u16* ra = sA + h * 4096 + rfo;
            const u16* rb = sB + h * 4096 + rfoB;
            bf16x8 af[4], bfr[4];
#pragma unroll
            for (int i = 0; i < 4; i++) af[i]  = *(const bf16x8*)(ra + i * 512);
#pragma unroll
            for (int i = 0; i < 4; i++) bfr[i] = *(const bf16x8*)(rb + i * 512);
#pragma unroll
            for (int mi = 0; mi < 4; mi++)
#pragma unroll
                for (int ni = 0; ni < 4; ni++)
                    acc[mi][ni] = __builtin_amdgcn_mfma_f32_16x16x32_bf16(
                        af[mi], bfr[ni], acc[mi][ni], 0, 0, 0);
        }
        __syncthreads();
    }
}

// ---------------------------------------------------------------------------
// 256x256-tile, 8-wave, m201-cadence pipelined GEMM core (16x16x32 MFMA).
// C = A @ B^T over K = T*64.
//
// LDS 128 KB: 2 tile-buffers x { A:[2 kh][256 r][32 c] u16, B: same @+16384 }.
// Bank swizzle: LDS[r][slot16] = G[r][slot16 ^ ((r>>1)&3)] via pre-swizzled
// global source (gload_lds dest linear); read-side XOR folds per-lane.
// Measured 0 bank conflicts (R3/R7).
//
// KEY CHANGE vs R7: staging goes to the OPPOSITE buffer (t+1 -> buf^1), so
// stage-landing is fully decoupled from read-draining: no lgkm-drain-for-
// staging barriers exist at all. Phase barriers bound wave skew to one
// phase; any staged region was last read >= 4 phases earlier => safe.
//
// 4 phases per K-tile t (buf b=t&1), each m201-style:
//   { JIT ds_read frags ; stage one 2-load unit of tile t+1 ;
//     [vmcnt(4) pre-bar at ph2/ph4] ; barrier ; lgkm(0)+sched_barrier ;
//     setprio(1) 16 MFMA setprio(0) ; barrier }
//   ph1: rd A(t,ks0,mi0-3)+B(t,ks0) [8] ; stage A(t+1)kh0 ; MFMA ks0 mi0-3
//   ph2: rd A(t,ks0,mi4-7)          [4] ; stage B(t+1)kh0 ; vm4 ; MFMA ks0 mi4-7
//   ph3: rd A(t,ks1,mi0-3)+B(t,ks1) [8] ; stage A(t+1)kh1 ; MFMA ks1 mi0-3
//   ph4: rd A(t,ks1,mi4-7)          [4] ; stage B(t+1)kh1 ; vm4 ; MFMA ks1 mi4-7
// B frags are register-reused across the mi4-7 phase (24 ds_read/tile, min).
//
// vmcnt(4) ledger (units of 2 loads, issue order per tile:
// [A(t+1)kh0, B(t+1)kh0, A(t+1)kh1, B(t+1)kh1]):
//   start of tile t: outstanding = [A(t)kh1, B(t)kh1] (4 loads)
//   ph2-end vm4: 8 outstanding -> retires [A(t)kh1,B(t)kh1]  = ph3's reads
//   ph4-end vm4: 8 outstanding -> retires [A(t+1)kh0,B(t+1)kh0] = next ph1's
// Pre-barrier placement => residency composes block-wide. Never 0 in-loop.
// Prologue stages tile0's 4 units then vmcnt(4)+barrier (leaves kh1 in
// flight = steady start-state). Tail clamps tn=t (same-byte rewrite).
// ---------------------------------------------------------------------------
__device__ __forceinline__ void gemm256_core(const u16* __restrict__ A,
                                             const u16* __restrict__ B,
                                             int lda, int ldb, int T,
                                             int rowA0, int rowB0,
                                             u16* lds,
                                             f32x4 acc[8][4],
                                             int wm, int wn)
{
    const int l = (int)threadIdx.x & 63;
    const int w = (int)threadIdx.x >> 6;

    // staging: wave w rows [w*32, w*32+32): lane -> row w*32+(l>>2), slot l&3
    const int srcswz = 8 * ((l & 3) ^ ((l >> 3) & 3));
    const u16* pA = A + (long)(rowA0 + w * 32 + (l >> 2)) * lda + srcswz;
    const u16* pB = B + (long)(rowB0 + w * 32 + (l >> 2)) * ldb + srcswz;
    const int dstb = w * 1024 + l * 8;

    // fragment read bases (swizzle constant per lane)
    const int fsw = 8 * ((l >> 4) ^ ((l >> 1) & 3));
    const int fA = (wm * 128 + (l & 15)) * 32 + fsw;
    const int fB = (wn * 64  + (l & 15)) * 32 + fsw;

    bf16x8 a4[4], b0[4], b1[4];

#define STG_A(tile, kh)                                                        \
    {                                                                          \
        const u16* s = pA + (long)(tile) * 64 + (kh) * 32;                     \
        u16* d = lds + (((tile) & 1) << 15) + ((kh) << 13) + dstb;             \
        gload_lds16(s, d);                                                     \
        gload_lds16(s + 16 * (long)lda, d + 512);                              \
    }
#define STG_B(tile, kh)                                                        \
    {                                                                          \
        const u16* s = pB + (long)(tile) * 64 + (kh) * 32;                     \
        u16* d = lds + (((tile) & 1) << 15) + ((kh) << 13) + 16384 + dstb;     \
        gload_lds16(s, d);                                                     \
        gload_lds16(s + 16 * (long)ldb, d + 512);                              \
    }
#define RD_A(dst, tile, ks, mih)                                               \
    {                                                                          \
        const u16* Ar = lds + (((tile) & 1) << 15) + ((ks) << 13) + fA +       \
                        (mih) * 2048;                                          \
        _Pragma("unroll")                                                      \
        for (int i = 0; i < 4; i++) dst[i] = *(const bf16x8*)(Ar + i * 512);   \
    }
#define RD_B(dst, tile, ks)                                                    \
    {                                                                          \
        const u16* Br = lds + (((tile) & 1) << 15) + ((ks) << 13) + 16384 + fB;\
        _Pragma("unroll")                                                      \
        for (int i = 0; i < 4; i++) dst[i] = *(const bf16x8*)(Br + i * 512);   \
    }
#define MF4(a_, b_, lo)                                                        \
    {                                                                          \
        __builtin_amdgcn_s_setprio(1);                                         \
        _Pragma("unroll")                                                      \
        for (int mi = 0; mi < 4; mi++)                                         \
            _Pragma("unroll")                                                  \
            for (int ni = 0; ni < 4; ni++)                                     \
                acc[(lo) + mi][ni] = __builtin_amdgcn_mfma_f32_16x16x32_bf16(  \
                    a_[mi], b_[ni], acc[(lo) + mi][ni], 0, 0, 0);              \
        __builtin_amdgcn_s_setprio(0);                                         \
    }
#define BAR()  __builtin_amdgcn_s_barrier()
#define LGKM0()                                                                \
    {                                                                          \
        asm volatile("s_waitcnt lgkmcnt(0)" ::: "memory");                     \
        __builtin_amdgcn_sched_barrier(0);                                     \
    }
#define VM4() asm volatile("s_waitcnt vmcnt(4)" ::: "memory")

    // ---- prologue: stage tile0 units [Akh0, Bkh0, Akh1, Bkh1] ----
    STG_A(0, 0); STG_B(0, 0); STG_A(0, 1); STG_B(0, 1);
    VM4();            // kh0 resident block-wide after barrier; kh1 in flight
    BAR();

    for (int t = 0; t < T; ++t) {
        const int tn = (t + 1 < T) ? t + 1 : t;   // tail: same-byte rewrite

        // ---- ph1: ks0 mi0-3 ----
        RD_A(a4, t, 0, 0); RD_B(b0, t, 0);
        STG_A(tn, 0);
        BAR();
        LGKM0();
        MF4(a4, b0, 0);
        BAR();

        // ---- ph2: ks0 mi4-7 (B reused) ----
        RD_A(a4, t, 0, 1);
        STG_B(tn, 0);
        VM4();                       // retires [A(t)kh1,B(t)kh1] -> ph3 safe
        BAR();
        LGKM0();
        MF4(a4, b0, 4);
        BAR();

        // ---- ph3: ks1 mi0-3 ----
        RD_A(a4, t, 1, 0); RD_B(b1, t, 1);
        STG_A(tn, 1);
        BAR();
        LGKM0();
        MF4(a4, b1, 0);
        BAR();

        // ---- ph4: ks1 mi4-7 (B reused) ----
        RD_A(a4, t, 1, 1);
        STG_B(tn, 1);
        VM4();                       // retires [A(t+1)kh0,B(t+1)kh0] -> next ph1
        BAR();
        LGKM0();
        MF4(a4, b1, 4);
        BAR();
    }
    asm volatile("s_waitcnt vmcnt(0)" ::: "memory");  // drain tail stages

#undef STG_A
#undef STG_B
#undef RD_A
#undef RD_B
#undef MF4
#undef BAR
#undef LGKM0
#undef VM4
}

// ---------------------------------------------------------------------------
// Kernel 1: fp32 -> bf16 casts
// ---------------------------------------------------------------------------
__global__ __launch_bounds__(256)
void cast6(const float* __restrict__ q, const float* __restrict__ k,
           const float* __restrict__ v, const float* __restrict__ wq,
           const float* __restrict__ wk, const float* __restrict__ wv,
           u16* __restrict__ qb, u16* __restrict__ kb, u16* __restrict__ vb,
           u16* __restrict__ wqb, u16* __restrict__ wkb, u16* __restrict__ wvb,
           int nqkv, int nw)
{
    const int z = blockIdx.y;
    const float* s; u16* d; int n;
    switch (z) {
        case 0:  s = q;  d = qb;  n = nqkv; break;
        case 1:  s = k;  d = kb;  n = nqkv; break;
        case 2:  s = v;  d = vb;  n = nqkv; break;
        case 3:  s = wq; d = wqb; n = nw;   break;
        case 4:  s = wk; d = wkb; n = nw;   break;
        default: s = wv; d = wvb; n = nw;   break;
    }
    long i = ((long)blockIdx.x * 256 + threadIdx.x) * 8;
    if (i >= n) return;
    float4 a = *(const float4*)(s + i);
    float4 b = *(const float4*)(s + i + 4);
    ushort4 o0, o1;
    o0.x = f2bf(a.x); o0.y = f2bf(a.y); o0.z = f2bf(a.z); o0.w = f2bf(a.w);
    o1.x = f2bf(b.x); o1.y = f2bf(b.y); o1.z = f2bf(b.z); o1.w = f2bf(b.w);
    *(ushort4*)(d + i)     = o0;
    *(ushort4*)(d + i + 4) = o1;
}

// ---------------------------------------------------------------------------
// Kernel 2: all three projections in one launch, grid (8, 32, 3):
//   z=0: qp = (q @ Wq^T + bq)*scale        (OUT rows = tokens)
//   z=1: kp = k @ Wk^T + bk                (OUT rows = tokens)
//   z=2: vpT = Wv @ v^T + bv, coalesced    (bm=bx over features, bn=by tokens)
// ---------------------------------------------------------------------------
__global__ __launch_bounds__(256, 2)
void proj_gemm(const u16* __restrict__ qb, const u16* __restrict__ kb,
               const u16* __restrict__ vb, const u16* __restrict__ wqb,
               const u16* __restrict__ wkb, const u16* __restrict__ wvb,
               const float* __restrict__ bq, const float* __restrict__ bk,
               const float* __restrict__ bv,
               u16* __restrict__ qp, u16* __restrict__ kp, u16* __restrict__ vpT)
{
    __shared__ __align__(16) u16 sA[8192];
    __shared__ __align__(16) u16 sB[8192];
    int bx, by, bz;
    xcd_swz(8, 32, bx, by, bz);
    const int z = bz;

    f32x4 acc[4][4] = {};
    const int lane = threadIdx.x & 63;
    const int wm   = (threadIdx.x >> 7) & 1;
    const int wn   = (threadIdx.x >> 6) & 1;

    if (z == 2) {
        // vpT = Wv @ v^T: A=Wv rows (features, M=1024 via bx), B=v rows (tokens)
        gemm_core(wvb, vb, 1024, 1024, 1024, bx, by, sA, sB, acc);
        const int m0 = bx * 128 + wm * 64 + ((lane >> 4) << 2);
        const int n0 = by * 128 + wn * 64 + (lane & 15);
#pragma unroll
        for (int mi = 0; mi < 4; mi++)
#pragma unroll
            for (int ni = 0; ni < 4; ni++) {
                const int gm = m0 + mi * 16;
                const int gn = n0 + ni * 16;
#pragma unroll
                for (int r = 0; r < 4; r++)
                    vpT[(long)(gm + r) * 4096 + gn] = f2bf(acc[mi][ni][r] + bv[gm + r]);
            }
        return;
    }

    const u16* A = (z == 0) ? qb : kb;
    const u16* B = (z == 0) ? wqb : wkb;
    const float* bias = (z == 0) ? bq : bk;
    u16* OUT = (z == 0) ? qp : kp;
    const float scale = (z == 0) ? 0.03125f : 1.0f;  // 1024^-0.5

    gemm_core(A, B, 1024, 1024, 1024, by, bx, sA, sB, acc);

    const int m0 = by * 128 + wm * 64 + ((lane >> 4) << 2);
    const int n0 = bx * 128 + wn * 64 + (lane & 15);
#pragma unroll
    for (int mi = 0; mi < 4; mi++)
#pragma unroll
        for (int ni = 0; ni < 4; ni++) {
            const int gm = m0 + mi * 16;
            const int gn = n0 + ni * 16;
            const float bb = bias[gn];
#pragma unroll
            for (int r = 0; r < 4; r++)
                OUT[(long)(gm + r) * 1024 + gn] = f2bf((acc[mi][ni][r] + bb) * scale);
        }
}

// ---------------------------------------------------------------------------
// Kernel 3: scores = qp @ kp^T -> bf16 S. 256x256 m201-cadence core.
// ---------------------------------------------------------------------------
__global__ __launch_bounds__(512, 2)
void score_gemm256(const u16* __restrict__ qp, const u16* __restrict__ kp,
                   u16* __restrict__ S)
{
    __shared__ __align__(16) u16 lds[65536];  // 128 KB

    const int flat = (int)blockIdx.x + ((int)blockIdx.y << 4);
    const int sfl = (flat & 7) * 32 + (flat >> 3);
    const int bx = sfl & 15;   // N tile
    const int by = sfl >> 4;   // M tile

    const int l  = (int)threadIdx.x & 63;
    const int w  = (int)threadIdx.x >> 6;
    const int wm = w >> 2;
    const int wn = w & 3;

    f32x4 acc[8][4] = {};
    gemm256_core(qp, kp, 1024, 1024, 16, by * 256, bx * 256, lds, acc, wm, wn);

    const int gm0 = by * 256 + wm * 128 + ((l >> 4) << 2);
    const int gn0 = bx * 256 + wn * 64 + (l & 15);
#pragma unroll
    for (int mi = 0; mi < 8; mi++)
#pragma unroll
        for (int ni = 0; ni < 4; ni++) {
            const int gm = gm0 + mi * 16;
            const int gn = gn0 + ni * 16;
#pragma unroll
            for (int r = 0; r < 4; r++)
                S[(long)(gm + r) * 4096 + gn] = f2bf(acc[mi][ni][r]);
        }
}

// ---------------------------------------------------------------------------
// Kernel 4: att = softmax(S_bf16, axis=-1) + bias, cast to bf16. Block per row.
// ---------------------------------------------------------------------------
__global__ __launch_bounds__(256)
void softmax_bias(const u16* __restrict__ S, const float* __restrict__ bias,
                  u16* __restrict__ att)
{
    const long row = blockIdx.x;
    const int tid = threadIdx.x;
    const u16* srow = S + row * 4096 + tid * 16;

    float v[16];
    {
        uint4 a = *(const uint4*)(srow);
        uint4 b = *(const uint4*)(srow + 8);
        unsigned w[8] = {a.x, a.y, a.z, a.w, b.x, b.y, b.z, b.w};
#pragma unroll
        for (int i = 0; i < 8; i++) {
            v[2 * i]     = bf2f(w[i] << 16);
            v[2 * i + 1] = bf2f(w[i] & 0xffff0000u);
        }
    }
    float mx = v[0];
#pragma unroll
    for (int i = 1; i < 16; i++) mx = fmaxf(mx, v[i]);
#pragma unroll
    for (int o = 32; o >= 1; o >>= 1) mx = fmaxf(mx, __shfl_xor(mx, o, 64));
    __shared__ float red[8];
    if ((tid & 63) == 0) red[tid >> 6] = mx;
    __syncthreads();
    mx = fmaxf(fmaxf(red[0], red[1]), fmaxf(red[2], red[3]));
    float sum = 0.f;
#pragma unroll
    for (int i = 0; i < 16; i++) { v[i] = __expf(v[i] - mx); sum += v[i]; }
#pragma unroll
    for (int o = 32; o >= 1; o >>= 1) sum += __shfl_xor(sum, o, 64);
    if ((tid & 63) == 0) red[4 + (tid >> 6)] = sum;
    __syncthreads();
    const float inv = 1.0f / (red[4] + red[5] + red[6] + red[7]);

    const float4* brow = (const float4*)(bias + row * 4096 + tid * 16);
    unsigned o[8];
#pragma unroll
    for (int i = 0; i < 4; i++) {
        float4 b = brow[i];
        unsigned lo = f2bf(v[4 * i + 0] * inv + b.x);
        unsigned hi = f2bf(v[4 * i + 1] * inv + b.y);
        o[2 * i] = lo | (hi << 16);
        lo = f2bf(v[4 * i + 2] * inv + b.z);
        hi = f2bf(v[4 * i + 3] * inv + b.w);
        o[2 * i + 1] = lo | (hi << 16);
    }
    u16* arow = att + row * 4096 + tid * 16;
    *(uint4*)(arow)     = make_uint4(o[0], o[1], o[2], o[3]);
    *(uint4*)(arow + 8) = make_uint4(o[4], o[5], o[6], o[7]);
}

// ---------------------------------------------------------------------------
// Kernel 5: split-K=4: P[z] = att[:, z*1024..] @ vpT[:, z*1024..]^T, fp32.
// 256x256 m201-cadence core. Grid (4, 16, 4) = 256 blocks, 1/CU.
// ---------------------------------------------------------------------------
__global__ __launch_bounds__(512, 2)
void out_gemm256(const u16* __restrict__ att, const u16* __restrict__ vpT,
                 float* __restrict__ P)
{
    __shared__ __align__(16) u16 lds[65536];  // 128 KB

    int bx, by, bz;
    xcd_swz(4, 16, bx, by, bz);
    const u16* A = att + bz * 1024;
    const u16* B = vpT + bz * 1024;
    float* O = P + (long)bz * 4096 * 1024;

    const int l  = (int)threadIdx.x & 63;
    const int w  = (int)threadIdx.x >> 6;
    const int wm = w >> 2;
    const int wn = w & 3;

    f32x4 acc[8][4] = {};
    gemm256_core(A, B, 4096, 4096, 16, by * 256, bx * 256, lds, acc, wm, wn);

    const int gm0 = by * 256 + wm * 128 + ((l >> 4) << 2);
    const int gn0 = bx * 256 + wn * 64 + (l & 15);
#pragma unroll
    for (int mi = 0; mi < 8; mi++)
#pragma unroll
        for (int ni = 0; ni < 4; ni++) {
            const int gm = gm0 + mi * 16;
            const int gn = gn0 + ni * 16;
#pragma unroll
            for (int r = 0; r < 4; r++)
                O[(long)(gm + r) * 1024 + gn] = acc[mi][ni][r];
        }
}

// ---------------------------------------------------------------------------
// Kernel 6: out = P0 + P1 + P2 + P3  (fp32), 4096x1024
// ---------------------------------------------------------------------------
__global__ __launch_bounds__(256)
void addp4(const float* __restrict__ P, float* __restrict__ O)
{
    long i = ((long)blockIdx.x * 256 + threadIdx.x) * 4;
    const long st = 4194304;
    float4 a = *(const float4*)(P + i);
    float4 b = *(const float4*)(P + st + i);
    float4 c = *(const float4*)(P + 2 * st + i);
    float4 d = *(const float4*)(P + 3 * st + i);
    float4 r;
    r.x = (a.x + b.x) + (c.x + d.x);
    r.y = (a.y + b.y) + (c.y + d.y);
    r.z = (a.z + b.z) + (c.z + d.z);
    r.w = (a.w + b.w) + (c.w + d.w);
    *(float4*)(O + i) = r;
}

// ---------------------------------------------------------------------------
extern "C" void kernel_launch(void* const* d_in, const int* in_sizes, int n_in,
                              void* d_out, int out_size, void* d_ws, size_t ws_size,
                              hipStream_t stream)
{
    const float* q    = (const float*)d_in[0];
    const float* k    = (const float*)d_in[1];
    const float* v    = (const float*)d_in[2];
    const float* bias = (const float*)d_in[3];
    const float* Wq   = (const float*)d_in[4];
    const float* bq   = (const float*)d_in[5];
    const float* Wk   = (const float*)d_in[6];
    const float* bk   = (const float*)d_in[7];
    const float* Wv   = (const float*)d_in[8];
    const float* bv   = (const float*)d_in[9];
    float* out = (float*)d_out;

    uint8_t* ws = (uint8_t*)d_ws;
    const size_t MB = 1u << 20;
    // layout (118 MB):
    //   [0,8)    qb   [8,16) kb   [16,24) vb        (dead after proj)
    //   [24,26)  wqb  [26,28) wkb [28,30) wvb       (dead after proj)
    //   [30,38)  qp   [38,46) kp                    (dead after score)
    //   [46,54)  vpT
    //   [54,86)  S (bf16 scores, 32MB)              (dead after softmax)
    //   [0,32)   att (bf16, 32MB) -- aliases dead qb/kb/vb region
    //   [54,118) P (4x fp32 partials, 16MB each) -- aliases dead S
    u16* qb  = (u16*)(ws);
    u16* kb  = (u16*)(ws + 8 * MB);
    u16* vb  = (u16*)(ws + 16 * MB);
    u16* wqb = (u16*)(ws + 24 * MB);
    u16* wkb = (u16*)(ws + 26 * MB);
    u16* wvb = (u16*)(ws + 28 * MB);
    u16* qp  = (u16*)(ws + 30 * MB);
    u16* kp  = (u16*)(ws + 38 * MB);
    u16* vpT = (u16*)(ws + 46 * MB);
    u16* S   = (u16*)(ws + 54 * MB);
    u16* att = (u16*)(ws);
    float* P = (float*)(ws + 54 * MB);

    cast6<<<dim3(2048, 6), 256, 0, stream>>>(q, k, v, Wq, Wk, Wv,
                                             qb, kb, vb, wqb, wkb, wvb,
                                             4096 * 1024, 1024 * 1024);
    proj_gemm<<<dim3(8, 32, 3), 256, 0, stream>>>(qb, kb, vb, wqb, wkb, wvb,
                                                  bq, bk, bv, qp, kp, vpT);
    score_gemm256<<<dim3(16, 16), 512, 0, stream>>>(qp, kp, S);
    softmax_bias<<<dim3(4096), 256, 0, stream>>>(S, bias, att);
    out_gemm256<<<dim3(4, 16, 4), 512, 0, stream>>>(att, vpT, P);
    addp4<<<dim3(4096), 256, 0, stream>>>(P, out);
}